// Round 14
// baseline (952.462 us; speedup 1.0000x reference)
//
#include <hip/hip_runtime.h>
#include <hip/hip_bf16.h>
#include <cstdint>

#define S_LEN 2048
#define HIDDEN 4096
#define NH 32
#define NKV 8
#define HD 128
#define BATCH 2
#define MROWS (BATCH * S_LEN)   // 4096

typedef float f32x4 __attribute__((ext_vector_type(4)));
typedef __bf16 bf16x8 __attribute__((ext_vector_type(8)));
typedef __bf16 bf16x4 __attribute__((ext_vector_type(4)));

static __device__ inline f32x4 mfma16(bf16x8 a, bf16x8 b, f32x4 c) {
    return __builtin_amdgcn_mfma_f32_16x16x32_bf16(a, b, c, 0, 0, 0);
}

// async global->LDS, 16B per lane; LDS dest = wave-uniform base + lane*16
static __device__ inline void gl_lds16(const __bf16* g, __bf16* l) {
    __builtin_amdgcn_global_load_lds(
        (const __attribute__((address_space(1))) void*)g,
        (__attribute__((address_space(3))) void*)l, 16, 0, 0);
}

#define LGKM0()  asm volatile("s_waitcnt lgkmcnt(0)" ::: "memory")
#define SCHEDB() __builtin_amdgcn_sched_barrier(0)
#define SBAR()   __builtin_amdgcn_s_barrier()

static __device__ inline void conv8(const float* src, __bf16* dst, int i) {
    const float4* p = (const float4*)src + (size_t)i * 2;
    float4 a = p[0], b = p[1];
    bf16x8 v;
    v[0] = (__bf16)a.x; v[1] = (__bf16)a.y; v[2] = (__bf16)a.z; v[3] = (__bf16)a.w;
    v[4] = (__bf16)b.x; v[5] = (__bf16)b.y; v[6] = (__bf16)b.z; v[7] = (__bf16)b.w;
    ((bf16x8*)dst)[i] = v;
}

// fp32 -> bf16 bulk convert, single segment
__global__ __launch_bounds__(256) void conv_f32_bf16(const float* __restrict__ in,
                                                     __bf16* __restrict__ out, int n8) {
    int i = blockIdx.x * 256 + threadIdx.x;
    if (i >= n8) return;
    conv8(in, out, i);
}

// fused 4-segment fp32 -> bf16 convert (block-uniform segment selection)
__global__ __launch_bounds__(256) void conv4(const float* __restrict__ s0, __bf16* __restrict__ d0, int b0,
                                             const float* __restrict__ s1, __bf16* __restrict__ d1, int b1,
                                             const float* __restrict__ s2, __bf16* __restrict__ d2, int b2,
                                             const float* __restrict__ s3, __bf16* __restrict__ d3) {
    int blk = blockIdx.x;
    const float* s; __bf16* d; int base;
    if (blk < b0)                { s = s0; d = d0; base = blk; }
    else if (blk < b0 + b1)      { s = s1; d = d1; base = blk - b0; }
    else if (blk < b0 + b1 + b2) { s = s2; d = d2; base = blk - b0 - b1; }
    else                         { s = s3; d = d3; base = blk - b0 - b1 - b2; }
    conv8(s, d, base * 256 + threadIdx.x);
}

// BM x 256 x K GEMM, C[m,n] = sum_k A[m,k]*B[n,k], bf16 in, 8 waves (512 thr).
// Round-7 proven structure: double-buffered LDS, ^(row&7) 16B-slot XOR swizzle,
// 4 phases/K-tile, counted vmcnt once per K-tile, raw barriers, setprio MFMA.
// MODE 0: bf16 C flat. MODE 1: fp32 C flat. MODE 3: KV routing (K flat / V transposed).
template<int MODE, int BM>
__global__ __launch_bounds__(512, 2) void gemm256(const __bf16* __restrict__ A,
                                                  const __bf16* __restrict__ B,
                                                  float* __restrict__ Cf,
                                                  __bf16* __restrict__ Qo,
                                                  __bf16* __restrict__ Ko,
                                                  __bf16* __restrict__ Vo,
                                                  int N, int K, int nbx) {
    constexpr int MF = BM / 32;
    constexpr int MH = BM / 64;
    __shared__ __bf16 As[2][BM * 64];
    __shared__ __bf16 Bs[2][256 * 64];
    const int tid = threadIdx.x, lane = tid & 63;
    const int lq = lane & 15, hi2 = lane >> 4;
    const int wv = tid >> 6;
    const int wr = wv >> 2, wc = wv & 3;

    const int cpx = gridDim.x >> 3;
    const int bid = blockIdx.x;
    const int swz = (bid & 7) * cpx + (bid >> 3);
    const int bx = swz % nbx, by = swz / nbx;
    const int brow = by * BM, bcol = bx * 256;

    f32x4 acc[MF][4] = {};
    bf16x8 af[MH][2], bfr[2][2];
    const int NT = K >> 6;

    auto stageA = [&](int bb, int kt, int roff) {
        #pragma unroll
        for (int r = 0; r < 2; ++r) {
            int i = r * 512 + tid;
            int row = i >> 3, sl = i & 7, lsl = sl ^ (row & 7);
            gl_lds16(A + (size_t)(brow + roff + row) * K + kt * 64 + lsl * 8,
                     &As[bb][roff * 64 + i * 8]);
        }
    };
    auto stageB = [&](int bb, int kt, int roff) {
        #pragma unroll
        for (int r = 0; r < 2; ++r) {
            int i = r * 512 + tid;
            int row = i >> 3, sl = i & 7, lsl = sl ^ (row & 7);
            gl_lds16(B + (size_t)(bcol + roff + row) * K + kt * 64 + lsl * 8,
                     &Bs[bb][roff * 64 + i * 8]);
        }
    };
    auto loadA = [&](int bb, int mq) {
        #pragma unroll
        for (int mi = 0; mi < MH; ++mi) {
            int row = wr * (BM / 2) + (mq * MH + mi) * 16 + lq;
            #pragma unroll
            for (int kk = 0; kk < 2; ++kk) {
                int lsl = (kk * 4 + hi2) ^ (row & 7);
                af[mi][kk] = *(const bf16x8*)&As[bb][row * 64 + lsl * 8];
            }
        }
    };
    auto loadB = [&](int bb, int nq) {
        #pragma unroll
        for (int ni = 0; ni < 2; ++ni) {
            int row = wc * 64 + (nq * 2 + ni) * 16 + lq;
            #pragma unroll
            for (int kk = 0; kk < 2; ++kk) {
                int lsl = (kk * 4 + hi2) ^ (row & 7);
                bfr[ni][kk] = *(const bf16x8*)&Bs[bb][row * 64 + lsl * 8];
            }
        }
    };
    auto mmaq = [&](int mq, int nq) {
        __builtin_amdgcn_s_setprio(1);
        #pragma unroll
        for (int kk = 0; kk < 2; ++kk)
            #pragma unroll
            for (int mi = 0; mi < MH; ++mi)
                #pragma unroll
                for (int ni = 0; ni < 2; ++ni)
                    acc[mq * MH + mi][nq * 2 + ni] =
                        mfma16(af[mi][kk], bfr[ni][kk], acc[mq * MH + mi][nq * 2 + ni]);
        __builtin_amdgcn_s_setprio(0);
    };

    stageA(0, 0, 0);
    if constexpr (BM == 256) stageA(0, 0, 128);
    stageB(0, 0, 0);
    stageB(0, 0, 128);

    for (int t = 0; t < NT; ++t) {
        const int cur = t & 1, nxt = cur ^ 1;
        const int tn = (t + 1 < NT) ? t + 1 : NT - 1;
        stageA(nxt, tn, 0);
        if constexpr (BM == 256) stageA(nxt, tn, 128);
        stageB(nxt, tn, 0);
        if constexpr (BM == 256) { asm volatile("s_waitcnt vmcnt(6)" ::: "memory"); }
        else                     { asm volatile("s_waitcnt vmcnt(4)" ::: "memory"); }
        SBAR(); SCHEDB();
        loadA(cur, 0); loadB(cur, 0);
        LGKM0(); SCHEDB();
        mmaq(0, 0);
        SBAR(); SCHEDB();
        loadB(cur, 1);
        stageB(nxt, tn, 128);
        SBAR(); SCHEDB();
        LGKM0(); SCHEDB();
        mmaq(0, 1);
        SBAR(); SCHEDB();
        loadA(cur, 1);
        SBAR(); SCHEDB();
        LGKM0(); SCHEDB();
        mmaq(1, 1);
        SBAR(); SCHEDB();
        loadB(cur, 0);
        SBAR(); SCHEDB();
        LGKM0(); SCHEDB();
        mmaq(1, 0);
        SBAR(); SCHEDB();
    }

    #pragma unroll
    for (int m = 0; m < MF; ++m) {
        #pragma unroll
        for (int n = 0; n < 4; ++n) {
            int row0 = brow + wr * (BM / 2) + m * 16 + (hi2 << 2);
            int col  = bcol + wc * 64 + n * 16 + lq;
            if constexpr (MODE == 3) {
                if (col < NKV * HD) {
                    #pragma unroll
                    for (int j = 0; j < 4; ++j)
                        Ko[(size_t)(row0 + j) * (NKV * HD) + col] = (__bf16)acc[m][n][j];
                } else {
                    int c2 = col - NKV * HD;
                    int hkv = c2 >> 7, d = c2 & (HD - 1);
                    int bb2 = row0 >> 11, s = row0 & (S_LEN - 1);
                    bf16x4 t4;
                    #pragma unroll
                    for (int j = 0; j < 4; ++j) t4[j] = (__bf16)acc[m][n][j];
                    *(bf16x4*)&Vo[((size_t)((bb2 * NKV + hkv) * HD + d)) * S_LEN + s] = t4;
                }
            } else if constexpr (MODE == 1) {
                #pragma unroll
                for (int j = 0; j < 4; ++j)
                    Cf[(size_t)(row0 + j) * N + col] = acc[m][n][j];
            } else {
                #pragma unroll
                for (int j = 0; j < 4; ++j)
                    Qo[(size_t)(row0 + j) * N + col] = (__bf16)acc[m][n][j];
            }
        }
    }
}

// in-place RoPE on bf16 [MROWS][nheads*HD]; cos/sin fp32 (B,S,HD), cos[d]==cos[d+64]
__global__ __launch_bounds__(256) void rope_kernel(__bf16* __restrict__ X,
                                                   const float* __restrict__ ct,
                                                   const float* __restrict__ st,
                                                   int nheads, int total) {
    int idx = blockIdx.x * 256 + threadIdx.x;
    if (idx >= total) return;
    int d  = idx & 63;
    int hh = (idx >> 6) % nheads;
    int m  = idx / (64 * nheads);
    __bf16* p = X + (size_t)m * (nheads * HD) + hh * HD;
    float c = ct[(size_t)m * HD + d];
    float s = st[(size_t)m * HD + d];
    float x1 = (float)p[d], x2 = (float)p[d + 64];
    p[d]      = (__bf16)(x1 * c - x2 * s);
    p[d + 64] = (__bf16)(x2 * c + x1 * s);
}

// flash attention, transposed-S, QB=128 (2 m-tiles/wave), UNPAIRED 1024 blocks
// (longest-first) -> 4 resident blocks/CU (LDS 37.1KB, launch_bounds(256,4)).
// Pl shared across m-tiles (interleaved write->fence->read; per-wave, DS in-order).
// RoPE-Q fused; exp2 softmax; defer-max THR=8; diagonal-only masking;
// KB=32 double-buffered, counted vmcnt(4), raw barriers; setprio MFMA clusters.
__global__ __launch_bounds__(256, 4) void attn_kernel(const __bf16* __restrict__ Q,
                                                      const __bf16* __restrict__ K,
                                                      const __bf16* __restrict__ V,
                                                      __bf16* __restrict__ O,
                                                      const float* __restrict__ ct,
                                                      const float* __restrict__ st) {
    constexpr int QB = 128, KB = 32;
    constexpr int nqb = S_LEN / QB;              // 16
    const int cpx = gridDim.x >> 3;              // 128
    const int b0 = blockIdx.x;
    const int bid = (b0 & 7) * cpx + (b0 >> 3);
    const int qb  = nqb - 1 - (bid % nqb);       // longest blocks dispatch first
    const int h   = (bid / nqb) % NH;
    const int b   = bid / (nqb * NH);
    const int hkv = h >> 2;
    const int tid = threadIdx.x, lane = tid & 63, w = tid >> 6;
    const int lq = lane & 15, hi2 = lane >> 4;
    const int q0 = qb * QB, qrow_lo = q0 + w * 32;

    __shared__ __bf16 Ks[2][KB * HD];   // [32][128], phys slot s of row r = logical s^(r&7)
    __shared__ __bf16 Vt[2][HD * KB];   // [128][32], phys slot s of row d = logical s^(d&3)
    __shared__ __bf16 Pl[4][16][40];    // [wave][q][kv] shared across m-tiles

    const int nkb = 4 * (qb + 1);

    auto stage = [&](int bb, int k0s) {          // 4 DMA issues/thread
        #pragma unroll
        for (int r = 0; r < 2; ++r) {
            int i = r * 256 + tid;
            {   int row = i >> 4, sl = i & 15, lsl = sl ^ (row & 7);
                gl_lds16(&K[((size_t)(b * S_LEN + k0s + row)) * (NKV * HD) + hkv * HD + lsl * 8],
                         &Ks[bb][i * 8]); }
            {   int d = i >> 2, sl = i & 3, lsl = sl ^ (d & 3);
                gl_lds16(&V[((size_t)((b * NKV + hkv) * HD + d)) * S_LEN + k0s + lsl * 8],
                         &Vt[bb][i * 8]); }
        }
    };

    const float c2 = 0.08838834764831843f * 1.4426950408889634f;  // scale * log2(e)

    // Q fragments: load raw Q, apply RoPE + exp2 prescale in-register.
    // chunk c holds d in [c*32+hi2*8, +8); rotation partner of chunk c is c+2.
    bf16x8 qf[2][4];
    #pragma unroll
    for (int mt = 0; mt < 2; ++mt) {
        int row = qrow_lo + mt * 16 + lq;
        const __bf16* qp = Q + ((size_t)(b * S_LEN + row)) * (NH * HD) + h * HD + hi2 * 8;
        const float* cp = ct + ((size_t)(b * S_LEN + row)) * HD + hi2 * 8;
        const float* sp = st + ((size_t)(b * S_LEN + row)) * HD + hi2 * 8;
        #pragma unroll
        for (int c = 0; c < 2; ++c) {
            bf16x8 lo = *(const bf16x8*)(qp + c * 32);
            bf16x8 hi = *(const bf16x8*)(qp + c * 32 + 64);
            f32x4 c0 = *(const f32x4*)(cp + c * 32);
            f32x4 c1 = *(const f32x4*)(cp + c * 32 + 4);
            f32x4 s0 = *(const f32x4*)(sp + c * 32);
            f32x4 s1 = *(const f32x4*)(sp + c * 32 + 4);
            bf16x8 rlo, rhi;
            #pragma unroll
            for (int e = 0; e < 8; ++e) {
                float cc = ((e < 4) ? c0[e] : c1[e - 4]) * c2;
                float ss = ((e < 4) ? s0[e] : s1[e - 4]) * c2;
                float xl = (float)lo[e], xh = (float)hi[e];
                rlo[e] = (__bf16)(xl * cc - xh * ss);
                rhi[e] = (__bf16)(xh * cc + xl * ss);
            }
            qf[mt][c]     = rlo;
            qf[mt][c + 2] = rhi;
        }
    }

    f32x4 o_acc[2][8] = {};
    float m_r[2] = {-1e30f, -1e30f}, l_r[2] = {0.f, 0.f};

    stage(0, 0);
    #pragma unroll 1
    for (int kb = 0; kb < nkb; ++kb) {
        int kn = (kb + 1 < nkb) ? kb + 1 : kb;   // clamp: keep vmcnt count uniform
        stage((kb + 1) & 1, kn * KB);
        asm volatile("s_waitcnt vmcnt(4)" ::: "memory");
        SBAR(); SCHEDB();
        const int cur = kb & 1;
        const int k0  = kb * KB;
        const __bf16* ks = &Ks[cur][0];
        const __bf16* vt = &Vt[cur][0];

        // S^T: 32 kv-rows x 16 q-cols per mt; kf shared across both m-tiles
        f32x4 sc[2][2] = {};
        __builtin_amdgcn_s_setprio(1);
        #pragma unroll
        for (int t = 0; t < 2; ++t) {
            int krow = t * 16 + lq;
            #pragma unroll
            for (int c = 0; c < 4; ++c) {
                int psl = (c * 4 + hi2) ^ (krow & 7);
                bf16x8 kf = *(const bf16x8*)&ks[krow * HD + psl * 8];
                sc[0][t] = mfma16(kf, qf[0][c], sc[0][t]);
                sc[1][t] = mfma16(kf, qf[1][c], sc[1][t]);
            }
        }
        __builtin_amdgcn_s_setprio(0);

        // mask + online softmax + P write->fence->read per m-tile (Pl shared)
        bf16x8 pf[2];
        #pragma unroll
        for (int mt = 0; mt < 2; ++mt) {
            int q_abs = qrow_lo + mt * 16 + lq;
            if (k0 + KB - 1 > qrow_lo + mt * 16) {   // diagonal tile: apply causal mask
                #pragma unroll
                for (int t = 0; t < 2; ++t)
                    #pragma unroll
                    for (int j = 0; j < 4; ++j) {
                        int kv_abs = k0 + t * 16 + hi2 * 4 + j;
                        if (kv_abs > q_abs) sc[mt][t][j] = -1e30f;
                    }
            }
            float pmax = fmaxf(
                fmaxf(fmaxf(sc[mt][0][0], sc[mt][0][1]), fmaxf(sc[mt][0][2], sc[mt][0][3])),
                fmaxf(fmaxf(sc[mt][1][0], sc[mt][1][1]), fmaxf(sc[mt][1][2], sc[mt][1][3])));
            pmax = fmaxf(pmax, __shfl_xor(pmax, 16));
            pmax = fmaxf(pmax, __shfl_xor(pmax, 32));
            if (!__all(pmax - m_r[mt] <= 8.0f)) {    // defer-max: rescale only when needed
                float mn = fmaxf(m_r[mt], pmax);
                float sf = __builtin_amdgcn_exp2f(m_r[mt] - mn);
                m_r[mt] = mn;
                l_r[mt] *= sf;
                #pragma unroll
                for (int dt = 0; dt < 8; ++dt)
                    #pragma unroll
                    for (int j = 0; j < 4; ++j) o_acc[mt][dt][j] *= sf;
            }
            float rs = 0.f;
            #pragma unroll
            for (int t = 0; t < 2; ++t)
                #pragma unroll
                for (int j = 0; j < 4; ++j) {
                    float p = __builtin_amdgcn_exp2f(sc[mt][t][j] - m_r[mt]);
                    sc[mt][t][j] = p;
                    rs += p;
                }
            rs += __shfl_xor(rs, 16);
            rs += __shfl_xor(rs, 32);
            l_r[mt] += rs;
            // P write (this mt) -> fence -> read fragment; per-wave buffer,
            // per-lane-overlapping addrs keep compiler order; DS in-order per wave.
            #pragma unroll
            for (int t = 0; t < 2; ++t) {
                bf16x4 pw;
                #pragma unroll
                for (int j = 0; j < 4; ++j) pw[j] = (__bf16)sc[mt][t][j];
                *(bf16x4*)&Pl[w][lq][t * 16 + hi2 * 4] = pw;
            }
            LGKM0(); SCHEDB();
            pf[mt] = *(const bf16x8*)&Pl[w][lq][hi2 * 8];
        }

        // PV: 8 d-tiles; vf shared across both m-tiles
        __builtin_amdgcn_s_setprio(1);
        #pragma unroll
        for (int dt = 0; dt < 8; ++dt) {
            int vrow = dt * 16 + lq;
            int psl  = hi2 ^ (vrow & 3);
            bf16x8 vf = *(const bf16x8*)&vt[vrow * KB + psl * 8];
            o_acc[0][dt] = mfma16(vf, pf[0], o_acc[0][dt]);
            o_acc[1][dt] = mfma16(vf, pf[1], o_acc[1][dt]);
        }
        __builtin_amdgcn_s_setprio(0);
        LGKM0(); SCHEDB();     // all cur ds_reads complete before next-iter DMA targets it
        SBAR(); SCHEDB();
    }

    #pragma unroll
    for (int mt = 0; mt < 2; ++mt) {
        float inv = 1.0f / l_r[mt];
        int q_abs = qrow_lo + mt * 16 + lq;
        __bf16* op = O + ((size_t)(b * S_LEN + q_abs)) * (NH * HD) + h * HD;
        #pragma unroll
        for (int dt = 0; dt < 8; ++dt) {
            bf16x4 t4;
            #pragma unroll
            for (int j = 0; j < 4; ++j) t4[j] = (__bf16)(o_acc[mt][dt][j] * inv);
            *(bf16x4*)&op[dt * 16 + hi2 * 4] = t4;
        }
    }
}

extern "C" void kernel_launch(void* const* d_in, const int* in_sizes, int n_in,
                              void* d_out, int out_size, void* d_ws, size_t ws_size,
                              hipStream_t stream) {
    const float* X  = (const float*)d_in[0];
    // d_in[1] = attention_mask: exactly causal; applied analytically in attn_kernel
    const float* ct = (const float*)d_in[2];
    const float* st = (const float*)d_in[3];
    const float* Wq = (const float*)d_in[4];
    const float* Wk = (const float*)d_in[5];
    const float* Wv = (const float*)d_in[6];
    const float* Wo = (const float*)d_in[7];
    float* out = (float*)d_out;

    const size_t MEL  = (size_t)MROWS * HIDDEN;      // 16.78M
    const size_t KVEL = (size_t)MROWS * (NKV * HD);  // 4.19M
    const int NQKV = NH * HD + 2 * NKV * HD;         // 6144

    // workspace (134.2 MB), dead-buffer aliasing.
    // ORDERING CONSTRAINT: Wob aliases Xb -> Wo conversion must run AFTER the
    // Q/KV projections consume Xb.
    __bf16* Wqkv = (__bf16*)d_ws;                   // [6144][4096] -> reused as Ab
    __bf16* Xb   = Wqkv + (size_t)NQKV * HIDDEN;    // [4096][4096] -> reused as Wob
    __bf16* Qb   = Xb + MEL;
    __bf16* Kb   = Qb + MEL;
    __bf16* VtG  = Kb + KVEL;
    __bf16* Ab   = Wqkv;
    __bf16* Wob  = Xb;

    dim3 blk(256);
    // fused conversions: X->Xb, Wq/Wk/Wv -> Wqkv (contiguous regions)
    const int cbM = (int)(MEL / 8 / 256);    // 8192 blocks per MEL segment
    const int cbK = (int)(KVEL / 8 / 256);   // 2048 blocks per KVEL segment
    hipLaunchKernelGGL(conv4, dim3(2 * cbM + 2 * cbK), blk, 0, stream,
                       X,  Xb, cbM,
                       Wq, Wqkv, cbM,
                       Wk, Wqkv + (size_t)HIDDEN * HIDDEN, cbK,
                       Wv, Wqkv + (size_t)(HIDDEN + NKV * HD) * HIDDEN);

    // Q projection: 4096x4096x4096, 256 blocks (exact machine fill); Qb is pre-RoPE
    hipLaunchKernelGGL((gemm256<0, 256>), dim3(256), dim3(512), 0, stream,
                       Xb, Wqkv, nullptr, Qb, nullptr, nullptr, NH * HD, HIDDEN, 16);
    // KV projection: 4096x2048x4096, BM=128 -> 256 blocks (exact fill)
    hipLaunchKernelGGL((gemm256<3, 128>), dim3(256), dim3(512), 0, stream,
                       Xb, Wqkv + (size_t)HIDDEN * HIDDEN, nullptr, nullptr, Kb, VtG,
                       2 * NKV * HD, HIDDEN, 8);

    // RoPE applied to K only (Q roped in-register inside attn)
    hipLaunchKernelGGL(rope_kernel, dim3((MROWS * NKV * 64) / 256), blk, 0, stream,
                       Kb, ct, st, NKV, MROWS * NKV * 64);

    // Wo conversion into Xb's slot (X dead only after the projections above)
    hipLaunchKernelGGL(conv_f32_bf16, dim3(cbM), blk, 0, stream, Wo, Wob, (int)(MEL / 8));

    // attention: 16 qb x 32 heads x 2 batch = 1024 blocks, longest-first
    hipLaunchKernelGGL(attn_kernel, dim3(1024), blk, 0, stream, Qb, Kb, VtG, Ab, ct, st);

    // O projection: 4096x4096x4096 -> fp32 out, 256 blocks (exact fill)
    hipLaunchKernelGGL((gemm256<1, 256>), dim3(256), dim3(512), 0, stream,
                       Ab, Wob, out, nullptr, nullptr, nullptr, HIDDEN, HIDDEN, 16);
}

// Round 15
// 590.261 us; speedup vs baseline: 1.6136x; 1.6136x over previous
//
#include <hip/hip_runtime.h>
#include <hip/hip_bf16.h>
#include <cstdint>

#define S_LEN 2048
#define HIDDEN 4096
#define NH 32
#define NKV 8
#define HD 128
#define BATCH 2
#define MROWS (BATCH * S_LEN)   // 4096

typedef float f32x4 __attribute__((ext_vector_type(4)));
typedef __bf16 bf16x8 __attribute__((ext_vector_type(8)));
typedef __bf16 bf16x4 __attribute__((ext_vector_type(4)));

static __device__ inline f32x4 mfma16(bf16x8 a, bf16x8 b, f32x4 c) {
    return __builtin_amdgcn_mfma_f32_16x16x32_bf16(a, b, c, 0, 0, 0);
}

// async global->LDS, 16B per lane; LDS dest = wave-uniform base + lane*16
static __device__ inline void gl_lds16(const __bf16* g, __bf16* l) {
    __builtin_amdgcn_global_load_lds(
        (const __attribute__((address_space(1))) void*)g,
        (__attribute__((address_space(3))) void*)l, 16, 0, 0);
}

#define LGKM0()  asm volatile("s_waitcnt lgkmcnt(0)" ::: "memory")
#define SCHEDB() __builtin_amdgcn_sched_barrier(0)
#define SBAR()   __builtin_amdgcn_s_barrier()

static __device__ inline void conv8(const float* src, __bf16* dst, int i) {
    const float4* p = (const float4*)src + (size_t)i * 2;
    float4 a = p[0], b = p[1];
    bf16x8 v;
    v[0] = (__bf16)a.x; v[1] = (__bf16)a.y; v[2] = (__bf16)a.z; v[3] = (__bf16)a.w;
    v[4] = (__bf16)b.x; v[5] = (__bf16)b.y; v[6] = (__bf16)b.z; v[7] = (__bf16)b.w;
    ((bf16x8*)dst)[i] = v;
}

// fp32 -> bf16 bulk convert, single segment
__global__ __launch_bounds__(256) void conv_f32_bf16(const float* __restrict__ in,
                                                     __bf16* __restrict__ out, int n8) {
    int i = blockIdx.x * 256 + threadIdx.x;
    if (i >= n8) return;
    conv8(in, out, i);
}

// fused 4-segment fp32 -> bf16 convert (block-uniform segment selection)
__global__ __launch_bounds__(256) void conv4(const float* __restrict__ s0, __bf16* __restrict__ d0, int b0,
                                             const float* __restrict__ s1, __bf16* __restrict__ d1, int b1,
                                             const float* __restrict__ s2, __bf16* __restrict__ d2, int b2,
                                             const float* __restrict__ s3, __bf16* __restrict__ d3) {
    int blk = blockIdx.x;
    const float* s; __bf16* d; int base;
    if (blk < b0)                { s = s0; d = d0; base = blk; }
    else if (blk < b0 + b1)      { s = s1; d = d1; base = blk - b0; }
    else if (blk < b0 + b1 + b2) { s = s2; d = d2; base = blk - b0 - b1; }
    else                         { s = s3; d = d3; base = blk - b0 - b1 - b2; }
    conv8(s, d, base * 256 + threadIdx.x);
}

// BM x 256 x K GEMM, C[m,n] = sum_k A[m,k]*B[n,k], bf16 in, 8 waves (512 thr).
// Round-7 proven structure: double-buffered LDS, ^(row&7) 16B-slot XOR swizzle,
// 4 phases/K-tile, counted vmcnt once per K-tile, raw barriers, setprio MFMA.
// MODE 0: bf16 C flat. MODE 1: fp32 C flat. MODE 3: KV routing (K flat / V transposed).
template<int MODE, int BM>
__global__ __launch_bounds__(512, 2) void gemm256(const __bf16* __restrict__ A,
                                                  const __bf16* __restrict__ B,
                                                  float* __restrict__ Cf,
                                                  __bf16* __restrict__ Qo,
                                                  __bf16* __restrict__ Ko,
                                                  __bf16* __restrict__ Vo,
                                                  int N, int K, int nbx) {
    constexpr int MF = BM / 32;
    constexpr int MH = BM / 64;
    __shared__ __bf16 As[2][BM * 64];
    __shared__ __bf16 Bs[2][256 * 64];
    const int tid = threadIdx.x, lane = tid & 63;
    const int lq = lane & 15, hi2 = lane >> 4;
    const int wv = tid >> 6;
    const int wr = wv >> 2, wc = wv & 3;

    const int cpx = gridDim.x >> 3;
    const int bid = blockIdx.x;
    const int swz = (bid & 7) * cpx + (bid >> 3);
    const int bx = swz % nbx, by = swz / nbx;
    const int brow = by * BM, bcol = bx * 256;

    f32x4 acc[MF][4] = {};
    bf16x8 af[MH][2], bfr[2][2];
    const int NT = K >> 6;

    auto stageA = [&](int bb, int kt, int roff) {
        #pragma unroll
        for (int r = 0; r < 2; ++r) {
            int i = r * 512 + tid;
            int row = i >> 3, sl = i & 7, lsl = sl ^ (row & 7);
            gl_lds16(A + (size_t)(brow + roff + row) * K + kt * 64 + lsl * 8,
                     &As[bb][roff * 64 + i * 8]);
        }
    };
    auto stageB = [&](int bb, int kt, int roff) {
        #pragma unroll
        for (int r = 0; r < 2; ++r) {
            int i = r * 512 + tid;
            int row = i >> 3, sl = i & 7, lsl = sl ^ (row & 7);
            gl_lds16(B + (size_t)(bcol + roff + row) * K + kt * 64 + lsl * 8,
                     &Bs[bb][roff * 64 + i * 8]);
        }
    };
    auto loadA = [&](int bb, int mq) {
        #pragma unroll
        for (int mi = 0; mi < MH; ++mi) {
            int row = wr * (BM / 2) + (mq * MH + mi) * 16 + lq;
            #pragma unroll
            for (int kk = 0; kk < 2; ++kk) {
                int lsl = (kk * 4 + hi2) ^ (row & 7);
                af[mi][kk] = *(const bf16x8*)&As[bb][row * 64 + lsl * 8];
            }
        }
    };
    auto loadB = [&](int bb, int nq) {
        #pragma unroll
        for (int ni = 0; ni < 2; ++ni) {
            int row = wc * 64 + (nq * 2 + ni) * 16 + lq;
            #pragma unroll
            for (int kk = 0; kk < 2; ++kk) {
                int lsl = (kk * 4 + hi2) ^ (row & 7);
                bfr[ni][kk] = *(const bf16x8*)&Bs[bb][row * 64 + lsl * 8];
            }
        }
    };
    auto mmaq = [&](int mq, int nq) {
        __builtin_amdgcn_s_setprio(1);
        #pragma unroll
        for (int kk = 0; kk < 2; ++kk)
            #pragma unroll
            for (int mi = 0; mi < MH; ++mi)
                #pragma unroll
                for (int ni = 0; ni < 2; ++ni)
                    acc[mq * MH + mi][nq * 2 + ni] =
                        mfma16(af[mi][kk], bfr[ni][kk], acc[mq * MH + mi][nq * 2 + ni]);
        __builtin_amdgcn_s_setprio(0);
    };

    stageA(0, 0, 0);
    if constexpr (BM == 256) stageA(0, 0, 128);
    stageB(0, 0, 0);
    stageB(0, 0, 128);

    for (int t = 0; t < NT; ++t) {
        const int cur = t & 1, nxt = cur ^ 1;
        const int tn = (t + 1 < NT) ? t + 1 : NT - 1;
        stageA(nxt, tn, 0);
        if constexpr (BM == 256) stageA(nxt, tn, 128);
        stageB(nxt, tn, 0);
        if constexpr (BM == 256) { asm volatile("s_waitcnt vmcnt(6)" ::: "memory"); }
        else                     { asm volatile("s_waitcnt vmcnt(4)" ::: "memory"); }
        SBAR(); SCHEDB();
        loadA(cur, 0); loadB(cur, 0);
        LGKM0(); SCHEDB();
        mmaq(0, 0);
        SBAR(); SCHEDB();
        loadB(cur, 1);
        stageB(nxt, tn, 128);
        SBAR(); SCHEDB();
        LGKM0(); SCHEDB();
        mmaq(0, 1);
        SBAR(); SCHEDB();
        loadA(cur, 1);
        SBAR(); SCHEDB();
        LGKM0(); SCHEDB();
        mmaq(1, 1);
        SBAR(); SCHEDB();
        loadB(cur, 0);
        SBAR(); SCHEDB();
        LGKM0(); SCHEDB();
        mmaq(1, 0);
        SBAR(); SCHEDB();
    }

    #pragma unroll
    for (int m = 0; m < MF; ++m) {
        #pragma unroll
        for (int n = 0; n < 4; ++n) {
            int row0 = brow + wr * (BM / 2) + m * 16 + (hi2 << 2);
            int col  = bcol + wc * 64 + n * 16 + lq;
            if constexpr (MODE == 3) {
                if (col < NKV * HD) {
                    #pragma unroll
                    for (int j = 0; j < 4; ++j)
                        Ko[(size_t)(row0 + j) * (NKV * HD) + col] = (__bf16)acc[m][n][j];
                } else {
                    int c2 = col - NKV * HD;
                    int hkv = c2 >> 7, d = c2 & (HD - 1);
                    int bb2 = row0 >> 11, s = row0 & (S_LEN - 1);
                    bf16x4 t4;
                    #pragma unroll
                    for (int j = 0; j < 4; ++j) t4[j] = (__bf16)acc[m][n][j];
                    *(bf16x4*)&Vo[((size_t)((bb2 * NKV + hkv) * HD + d)) * S_LEN + s] = t4;
                }
            } else if constexpr (MODE == 1) {
                #pragma unroll
                for (int j = 0; j < 4; ++j)
                    Cf[(size_t)(row0 + j) * N + col] = acc[m][n][j];
            } else {
                #pragma unroll
                for (int j = 0; j < 4; ++j)
                    Qo[(size_t)(row0 + j) * N + col] = (__bf16)acc[m][n][j];
            }
        }
    }
}

// in-place RoPE on bf16 [MROWS][nheads*HD]; cos/sin fp32 (B,S,HD), cos[d]==cos[d+64]
__global__ __launch_bounds__(256) void rope_kernel(__bf16* __restrict__ X,
                                                   const float* __restrict__ ct,
                                                   const float* __restrict__ st,
                                                   int nheads, int total) {
    int idx = blockIdx.x * 256 + threadIdx.x;
    if (idx >= total) return;
    int d  = idx & 63;
    int hh = (idx >> 6) % nheads;
    int m  = idx / (64 * nheads);
    __bf16* p = X + (size_t)m * (nheads * HD) + hh * HD;
    float c = ct[(size_t)m * HD + d];
    float s = st[(size_t)m * HD + d];
    float x1 = (float)p[d], x2 = (float)p[d + 64];
    p[d]      = (__bf16)(x1 * c - x2 * s);
    p[d + 64] = (__bf16)(x2 * c + x1 * s);
}

// flash attention, transposed-S, QB=128 (2 m-tiles/wave), UNPAIRED 1024 blocks
// (longest-first). launch_bounds(256,3): ~170-reg cap — o_acc[2][8]+qf fit with
// NO scratch spill (r14's (256,4) capped at 128 regs and spilled o_acc: 5x slower).
// LDS 37.9KB -> 3 resident blocks/CU. Pl shared across m-tiles (write->fence->read).
// RoPE-Q fused; exp2 softmax; defer-max THR=8; diagonal-only masking;
// KB=32 double-buffered, counted vmcnt(4), raw barriers; setprio MFMA clusters.
__global__ __launch_bounds__(256, 3) void attn_kernel(const __bf16* __restrict__ Q,
                                                      const __bf16* __restrict__ K,
                                                      const __bf16* __restrict__ V,
                                                      __bf16* __restrict__ O,
                                                      const float* __restrict__ ct,
                                                      const float* __restrict__ st) {
    constexpr int QB = 128, KB = 32;
    constexpr int nqb = S_LEN / QB;              // 16
    const int cpx = gridDim.x >> 3;              // 128
    const int b0 = blockIdx.x;
    const int bid = (b0 & 7) * cpx + (b0 >> 3);
    const int qb  = nqb - 1 - (bid % nqb);       // longest blocks dispatch first
    const int h   = (bid / nqb) % NH;
    const int b   = bid / (nqb * NH);
    const int hkv = h >> 2;
    const int tid = threadIdx.x, lane = tid & 63, w = tid >> 6;
    const int lq = lane & 15, hi2 = lane >> 4;
    const int q0 = qb * QB, qrow_lo = q0 + w * 32;

    __shared__ __bf16 Ks[2][KB * HD];   // [32][128], phys slot s of row r = logical s^(r&7)
    __shared__ __bf16 Vt[2][HD * KB];   // [128][32], phys slot s of row d = logical s^(d&3)
    __shared__ __bf16 Pl[4][16][40];    // [wave][q][kv] shared across m-tiles

    const int nkb = 4 * (qb + 1);

    auto stage = [&](int bb, int k0s) {          // 4 DMA issues/thread
        #pragma unroll
        for (int r = 0; r < 2; ++r) {
            int i = r * 256 + tid;
            {   int row = i >> 4, sl = i & 15, lsl = sl ^ (row & 7);
                gl_lds16(&K[((size_t)(b * S_LEN + k0s + row)) * (NKV * HD) + hkv * HD + lsl * 8],
                         &Ks[bb][i * 8]); }
            {   int d = i >> 2, sl = i & 3, lsl = sl ^ (d & 3);
                gl_lds16(&V[((size_t)((b * NKV + hkv) * HD + d)) * S_LEN + k0s + lsl * 8],
                         &Vt[bb][i * 8]); }
        }
    };

    const float c2 = 0.08838834764831843f * 1.4426950408889634f;  // scale * log2(e)

    // Q fragments: load raw Q, apply RoPE + exp2 prescale in-register.
    // chunk c holds d in [c*32+hi2*8, +8); rotation partner of chunk c is c+2.
    bf16x8 qf[2][4];
    #pragma unroll
    for (int mt = 0; mt < 2; ++mt) {
        int row = qrow_lo + mt * 16 + lq;
        const __bf16* qp = Q + ((size_t)(b * S_LEN + row)) * (NH * HD) + h * HD + hi2 * 8;
        const float* cp = ct + ((size_t)(b * S_LEN + row)) * HD + hi2 * 8;
        const float* sp = st + ((size_t)(b * S_LEN + row)) * HD + hi2 * 8;
        #pragma unroll
        for (int c = 0; c < 2; ++c) {
            bf16x8 lo = *(const bf16x8*)(qp + c * 32);
            bf16x8 hi = *(const bf16x8*)(qp + c * 32 + 64);
            f32x4 c0 = *(const f32x4*)(cp + c * 32);
            f32x4 c1 = *(const f32x4*)(cp + c * 32 + 4);
            f32x4 s0 = *(const f32x4*)(sp + c * 32);
            f32x4 s1 = *(const f32x4*)(sp + c * 32 + 4);
            bf16x8 rlo, rhi;
            #pragma unroll
            for (int e = 0; e < 8; ++e) {
                float cc = ((e < 4) ? c0[e] : c1[e - 4]) * c2;
                float ss = ((e < 4) ? s0[e] : s1[e - 4]) * c2;
                float xl = (float)lo[e], xh = (float)hi[e];
                rlo[e] = (__bf16)(xl * cc - xh * ss);
                rhi[e] = (__bf16)(xh * cc + xl * ss);
            }
            qf[mt][c]     = rlo;
            qf[mt][c + 2] = rhi;
        }
    }

    f32x4 o_acc[2][8] = {};
    float m_r[2] = {-1e30f, -1e30f}, l_r[2] = {0.f, 0.f};

    stage(0, 0);
    #pragma unroll 1
    for (int kb = 0; kb < nkb; ++kb) {
        int kn = (kb + 1 < nkb) ? kb + 1 : kb;   // clamp: keep vmcnt count uniform
        stage((kb + 1) & 1, kn * KB);
        asm volatile("s_waitcnt vmcnt(4)" ::: "memory");
        SBAR(); SCHEDB();
        const int cur = kb & 1;
        const int k0  = kb * KB;
        const __bf16* ks = &Ks[cur][0];
        const __bf16* vt = &Vt[cur][0];

        // S^T: 32 kv-rows x 16 q-cols per mt; kf shared across both m-tiles
        f32x4 sc[2][2] = {};
        __builtin_amdgcn_s_setprio(1);
        #pragma unroll
        for (int t = 0; t < 2; ++t) {
            int krow = t * 16 + lq;
            #pragma unroll
            for (int c = 0; c < 4; ++c) {
                int psl = (c * 4 + hi2) ^ (krow & 7);
                bf16x8 kf = *(const bf16x8*)&ks[krow * HD + psl * 8];
                sc[0][t] = mfma16(kf, qf[0][c], sc[0][t]);
                sc[1][t] = mfma16(kf, qf[1][c], sc[1][t]);
            }
        }
        __builtin_amdgcn_s_setprio(0);

        // mask + online softmax + P write->fence->read per m-tile (Pl shared)
        bf16x8 pf[2];
        #pragma unroll
        for (int mt = 0; mt < 2; ++mt) {
            int q_abs = qrow_lo + mt * 16 + lq;
            if (k0 + KB - 1 > qrow_lo + mt * 16) {   // diagonal tile: apply causal mask
                #pragma unroll
                for (int t = 0; t < 2; ++t)
                    #pragma unroll
                    for (int j = 0; j < 4; ++j) {
                        int kv_abs = k0 + t * 16 + hi2 * 4 + j;
                        if (kv_abs > q_abs) sc[mt][t][j] = -1e30f;
                    }
            }
            float pmax = fmaxf(
                fmaxf(fmaxf(sc[mt][0][0], sc[mt][0][1]), fmaxf(sc[mt][0][2], sc[mt][0][3])),
                fmaxf(fmaxf(sc[mt][1][0], sc[mt][1][1]), fmaxf(sc[mt][1][2], sc[mt][1][3])));
            pmax = fmaxf(pmax, __shfl_xor(pmax, 16));
            pmax = fmaxf(pmax, __shfl_xor(pmax, 32));
            if (!__all(pmax - m_r[mt] <= 8.0f)) {    // defer-max: rescale only when needed
                float mn = fmaxf(m_r[mt], pmax);
                float sf = __builtin_amdgcn_exp2f(m_r[mt] - mn);
                m_r[mt] = mn;
                l_r[mt] *= sf;
                #pragma unroll
                for (int dt = 0; dt < 8; ++dt)
                    #pragma unroll
                    for (int j = 0; j < 4; ++j) o_acc[mt][dt][j] *= sf;
            }
            float rs = 0.f;
            #pragma unroll
            for (int t = 0; t < 2; ++t)
                #pragma unroll
                for (int j = 0; j < 4; ++j) {
                    float p = __builtin_amdgcn_exp2f(sc[mt][t][j] - m_r[mt]);
                    sc[mt][t][j] = p;
                    rs += p;
                }
            rs += __shfl_xor(rs, 16);
            rs += __shfl_xor(rs, 32);
            l_r[mt] += rs;
            // P write (this mt) -> fence -> read fragment; per-wave buffer,
            // per-lane-overlapping addrs keep compiler order; DS in-order per wave.
            #pragma unroll
            for (int t = 0; t < 2; ++t) {
                bf16x4 pw;
                #pragma unroll
                for (int j = 0; j < 4; ++j) pw[j] = (__bf16)sc[mt][t][j];
                *(bf16x4*)&Pl[w][lq][t * 16 + hi2 * 4] = pw;
            }
            LGKM0(); SCHEDB();
            pf[mt] = *(const bf16x8*)&Pl[w][lq][hi2 * 8];
        }

        // PV: 8 d-tiles; vf shared across both m-tiles
        __builtin_amdgcn_s_setprio(1);
        #pragma unroll
        for (int dt = 0; dt < 8; ++dt) {
            int vrow = dt * 16 + lq;
            int psl  = hi2 ^ (vrow & 3);
            bf16x8 vf = *(const bf16x8*)&vt[vrow * KB + psl * 8];
            o_acc[0][dt] = mfma16(vf, pf[0], o_acc[0][dt]);
            o_acc[1][dt] = mfma16(vf, pf[1], o_acc[1][dt]);
        }
        __builtin_amdgcn_s_setprio(0);
        LGKM0(); SCHEDB();     // all cur ds_reads complete before next-iter DMA targets it
        SBAR(); SCHEDB();
    }

    #pragma unroll
    for (int mt = 0; mt < 2; ++mt) {
        float inv = 1.0f / l_r[mt];
        int q_abs = qrow_lo + mt * 16 + lq;
        __bf16* op = O + ((size_t)(b * S_LEN + q_abs)) * (NH * HD) + h * HD;
        #pragma unroll
        for (int dt = 0; dt < 8; ++dt) {
            bf16x4 t4;
            #pragma unroll
            for (int j = 0; j < 4; ++j) t4[j] = (__bf16)(o_acc[mt][dt][j] * inv);
            *(bf16x4*)&op[dt * 16 + hi2 * 4] = t4;
        }
    }
}

extern "C" void kernel_launch(void* const* d_in, const int* in_sizes, int n_in,
                              void* d_out, int out_size, void* d_ws, size_t ws_size,
                              hipStream_t stream) {
    const float* X  = (const float*)d_in[0];
    // d_in[1] = attention_mask: exactly causal; applied analytically in attn_kernel
    const float* ct = (const float*)d_in[2];
    const float* st = (const float*)d_in[3];
    const float* Wq = (const float*)d_in[4];
    const float* Wk = (const float*)d_in[5];
    const float* Wv = (const float*)d_in[6];
    const float* Wo = (const float*)d_in[7];
    float* out = (float*)d_out;

    const size_t MEL  = (size_t)MROWS * HIDDEN;      // 16.78M
    const size_t KVEL = (size_t)MROWS * (NKV * HD);  // 4.19M
    const int NQKV = NH * HD + 2 * NKV * HD;         // 6144

    // workspace (134.2 MB), dead-buffer aliasing.
    // ORDERING CONSTRAINT: Wob aliases Xb -> Wo conversion must run AFTER the
    // Q/KV projections consume Xb.
    __bf16* Wqkv = (__bf16*)d_ws;                   // [6144][4096] -> reused as Ab
    __bf16* Xb   = Wqkv + (size_t)NQKV * HIDDEN;    // [4096][4096] -> reused as Wob
    __bf16* Qb   = Xb + MEL;
    __bf16* Kb   = Qb + MEL;
    __bf16* VtG  = Kb + KVEL;
    __bf16* Ab   = Wqkv;
    __bf16* Wob  = Xb;

    dim3 blk(256);
    // fused conversions: X->Xb, Wq/Wk/Wv -> Wqkv (contiguous regions)
    const int cbM = (int)(MEL / 8 / 256);    // 8192 blocks per MEL segment
    const int cbK = (int)(KVEL / 8 / 256);   // 2048 blocks per KVEL segment
    hipLaunchKernelGGL(conv4, dim3(2 * cbM + 2 * cbK), blk, 0, stream,
                       X,  Xb, cbM,
                       Wq, Wqkv, cbM,
                       Wk, Wqkv + (size_t)HIDDEN * HIDDEN, cbK,
                       Wv, Wqkv + (size_t)(HIDDEN + NKV * HD) * HIDDEN);

    // Q projection: 4096x4096x4096, 256 blocks (exact machine fill); Qb is pre-RoPE
    hipLaunchKernelGGL((gemm256<0, 256>), dim3(256), dim3(512), 0, stream,
                       Xb, Wqkv, nullptr, Qb, nullptr, nullptr, NH * HD, HIDDEN, 16);
    // KV projection: 4096x2048x4096, BM=128 -> 256 blocks (exact fill)
    hipLaunchKernelGGL((gemm256<3, 128>), dim3(256), dim3(512), 0, stream,
                       Xb, Wqkv + (size_t)HIDDEN * HIDDEN, nullptr, nullptr, Kb, VtG,
                       2 * NKV * HD, HIDDEN, 8);

    // RoPE applied to K only (Q roped in-register inside attn)
    hipLaunchKernelGGL(rope_kernel, dim3((MROWS * NKV * 64) / 256), blk, 0, stream,
                       Kb, ct, st, NKV, MROWS * NKV * 64);

    // Wo conversion into Xb's slot (X dead only after the projections above)
    hipLaunchKernelGGL(conv_f32_bf16, dim3(cbM), blk, 0, stream, Wo, Wob, (int)(MEL / 8));

    // attention: 16 qb x 32 heads x 2 batch = 1024 blocks, longest-first
    hipLaunchKernelGGL(attn_kernel, dim3(1024), blk, 0, stream, Qb, Kb, VtG, Ab, ct, st);

    // O projection: 4096x4096x4096 -> fp32 out, 256 blocks (exact fill)
    hipLaunchKernelGGL((gemm256<1, 256>), dim3(256), dim3(512), 0, stream,
                       Ab, Wob, out, nullptr, nullptr, nullptr, HIDDEN, HIDDEN, 16);
}

// Round 16
// 589.747 us; speedup vs baseline: 1.6150x; 1.0009x over previous
//
#include <hip/hip_runtime.h>
#include <hip/hip_bf16.h>
#include <cstdint>

#define S_LEN 2048
#define HIDDEN 4096
#define NH 32
#define NKV 8
#define HD 128
#define BATCH 2
#define MROWS (BATCH * S_LEN)   // 4096

typedef float f32x4 __attribute__((ext_vector_type(4)));
typedef __bf16 bf16x8 __attribute__((ext_vector_type(8)));
typedef __bf16 bf16x4 __attribute__((ext_vector_type(4)));

static __device__ inline f32x4 mfma16(bf16x8 a, bf16x8 b, f32x4 c) {
    return __builtin_amdgcn_mfma_f32_16x16x32_bf16(a, b, c, 0, 0, 0);
}

// async global->LDS, 16B per lane; LDS dest = wave-uniform base + lane*16
static __device__ inline void gl_lds16(const __bf16* g, __bf16* l) {
    __builtin_amdgcn_global_load_lds(
        (const __attribute__((address_space(1))) void*)g,
        (__attribute__((address_space(3))) void*)l, 16, 0, 0);
}

#define LGKM0()  asm volatile("s_waitcnt lgkmcnt(0)" ::: "memory")
#define SCHEDB() __builtin_amdgcn_sched_barrier(0)
#define SBAR()   __builtin_amdgcn_s_barrier()

static __device__ inline void conv8(const float* src, __bf16* dst, int i) {
    const float4* p = (const float4*)src + (size_t)i * 2;
    float4 a = p[0], b = p[1];
    bf16x8 v;
    v[0] = (__bf16)a.x; v[1] = (__bf16)a.y; v[2] = (__bf16)a.z; v[3] = (__bf16)a.w;
    v[4] = (__bf16)b.x; v[5] = (__bf16)b.y; v[6] = (__bf16)b.z; v[7] = (__bf16)b.w;
    ((bf16x8*)dst)[i] = v;
}

// fp32 -> bf16 bulk convert, single segment
__global__ __launch_bounds__(256) void conv_f32_bf16(const float* __restrict__ in,
                                                     __bf16* __restrict__ out, int n8) {
    int i = blockIdx.x * 256 + threadIdx.x;
    if (i >= n8) return;
    conv8(in, out, i);
}

// fused 4-segment fp32 -> bf16 convert (block-uniform segment selection)
__global__ __launch_bounds__(256) void conv4(const float* __restrict__ s0, __bf16* __restrict__ d0, int b0,
                                             const float* __restrict__ s1, __bf16* __restrict__ d1, int b1,
                                             const float* __restrict__ s2, __bf16* __restrict__ d2, int b2,
                                             const float* __restrict__ s3, __bf16* __restrict__ d3) {
    int blk = blockIdx.x;
    const float* s; __bf16* d; int base;
    if (blk < b0)                { s = s0; d = d0; base = blk; }
    else if (blk < b0 + b1)      { s = s1; d = d1; base = blk - b0; }
    else if (blk < b0 + b1 + b2) { s = s2; d = d2; base = blk - b0 - b1; }
    else                         { s = s3; d = d3; base = blk - b0 - b1 - b2; }
    conv8(s, d, base * 256 + threadIdx.x);
}

// BM x 256 x K GEMM, C[m,n] = sum_k A[m,k]*B[n,k], bf16 in, 8 waves (512 thr).
// Round-7 proven structure: double-buffered LDS, ^(row&7) 16B-slot XOR swizzle,
// 4 phases/K-tile, counted vmcnt once per K-tile, raw barriers, setprio MFMA.
// MODE 0: bf16 C flat. MODE 1: fp32 C flat. MODE 3: KV routing (K flat / V transposed).
template<int MODE, int BM>
__global__ __launch_bounds__(512, 2) void gemm256(const __bf16* __restrict__ A,
                                                  const __bf16* __restrict__ B,
                                                  float* __restrict__ Cf,
                                                  __bf16* __restrict__ Qo,
                                                  __bf16* __restrict__ Ko,
                                                  __bf16* __restrict__ Vo,
                                                  int N, int K, int nbx) {
    constexpr int MF = BM / 32;
    constexpr int MH = BM / 64;
    __shared__ __bf16 As[2][BM * 64];
    __shared__ __bf16 Bs[2][256 * 64];
    const int tid = threadIdx.x, lane = tid & 63;
    const int lq = lane & 15, hi2 = lane >> 4;
    const int wv = tid >> 6;
    const int wr = wv >> 2, wc = wv & 3;

    const int cpx = gridDim.x >> 3;
    const int bid = blockIdx.x;
    const int swz = (bid & 7) * cpx + (bid >> 3);
    const int bx = swz % nbx, by = swz / nbx;
    const int brow = by * BM, bcol = bx * 256;

    f32x4 acc[MF][4] = {};
    bf16x8 af[MH][2], bfr[2][2];
    const int NT = K >> 6;

    auto stageA = [&](int bb, int kt, int roff) {
        #pragma unroll
        for (int r = 0; r < 2; ++r) {
            int i = r * 512 + tid;
            int row = i >> 3, sl = i & 7, lsl = sl ^ (row & 7);
            gl_lds16(A + (size_t)(brow + roff + row) * K + kt * 64 + lsl * 8,
                     &As[bb][roff * 64 + i * 8]);
        }
    };
    auto stageB = [&](int bb, int kt, int roff) {
        #pragma unroll
        for (int r = 0; r < 2; ++r) {
            int i = r * 512 + tid;
            int row = i >> 3, sl = i & 7, lsl = sl ^ (row & 7);
            gl_lds16(B + (size_t)(bcol + roff + row) * K + kt * 64 + lsl * 8,
                     &Bs[bb][roff * 64 + i * 8]);
        }
    };
    auto loadA = [&](int bb, int mq) {
        #pragma unroll
        for (int mi = 0; mi < MH; ++mi) {
            int row = wr * (BM / 2) + (mq * MH + mi) * 16 + lq;
            #pragma unroll
            for (int kk = 0; kk < 2; ++kk) {
                int lsl = (kk * 4 + hi2) ^ (row & 7);
                af[mi][kk] = *(const bf16x8*)&As[bb][row * 64 + lsl * 8];
            }
        }
    };
    auto loadB = [&](int bb, int nq) {
        #pragma unroll
        for (int ni = 0; ni < 2; ++ni) {
            int row = wc * 64 + (nq * 2 + ni) * 16 + lq;
            #pragma unroll
            for (int kk = 0; kk < 2; ++kk) {
                int lsl = (kk * 4 + hi2) ^ (row & 7);
                bfr[ni][kk] = *(const bf16x8*)&Bs[bb][row * 64 + lsl * 8];
            }
        }
    };
    auto mmaq = [&](int mq, int nq) {
        __builtin_amdgcn_s_setprio(1);
        #pragma unroll
        for (int kk = 0; kk < 2; ++kk)
            #pragma unroll
            for (int mi = 0; mi < MH; ++mi)
                #pragma unroll
                for (int ni = 0; ni < 2; ++ni)
                    acc[mq * MH + mi][nq * 2 + ni] =
                        mfma16(af[mi][kk], bfr[ni][kk], acc[mq * MH + mi][nq * 2 + ni]);
        __builtin_amdgcn_s_setprio(0);
    };

    stageA(0, 0, 0);
    if constexpr (BM == 256) stageA(0, 0, 128);
    stageB(0, 0, 0);
    stageB(0, 0, 128);

    for (int t = 0; t < NT; ++t) {
        const int cur = t & 1, nxt = cur ^ 1;
        const int tn = (t + 1 < NT) ? t + 1 : NT - 1;
        stageA(nxt, tn, 0);
        if constexpr (BM == 256) stageA(nxt, tn, 128);
        stageB(nxt, tn, 0);
        if constexpr (BM == 256) { asm volatile("s_waitcnt vmcnt(6)" ::: "memory"); }
        else                     { asm volatile("s_waitcnt vmcnt(4)" ::: "memory"); }
        SBAR(); SCHEDB();
        loadA(cur, 0); loadB(cur, 0);
        LGKM0(); SCHEDB();
        mmaq(0, 0);
        SBAR(); SCHEDB();
        loadB(cur, 1);
        stageB(nxt, tn, 128);
        SBAR(); SCHEDB();
        LGKM0(); SCHEDB();
        mmaq(0, 1);
        SBAR(); SCHEDB();
        loadA(cur, 1);
        SBAR(); SCHEDB();
        LGKM0(); SCHEDB();
        mmaq(1, 1);
        SBAR(); SCHEDB();
        loadB(cur, 0);
        SBAR(); SCHEDB();
        LGKM0(); SCHEDB();
        mmaq(1, 0);
        SBAR(); SCHEDB();
    }

    #pragma unroll
    for (int m = 0; m < MF; ++m) {
        #pragma unroll
        for (int n = 0; n < 4; ++n) {
            int row0 = brow + wr * (BM / 2) + m * 16 + (hi2 << 2);
            int col  = bcol + wc * 64 + n * 16 + lq;
            if constexpr (MODE == 3) {
                if (col < NKV * HD) {
                    #pragma unroll
                    for (int j = 0; j < 4; ++j)
                        Ko[(size_t)(row0 + j) * (NKV * HD) + col] = (__bf16)acc[m][n][j];
                } else {
                    int c2 = col - NKV * HD;
                    int hkv = c2 >> 7, d = c2 & (HD - 1);
                    int bb2 = row0 >> 11, s = row0 & (S_LEN - 1);
                    bf16x4 t4;
                    #pragma unroll
                    for (int j = 0; j < 4; ++j) t4[j] = (__bf16)acc[m][n][j];
                    *(bf16x4*)&Vo[((size_t)((bb2 * NKV + hkv) * HD + d)) * S_LEN + s] = t4;
                }
            } else if constexpr (MODE == 1) {
                #pragma unroll
                for (int j = 0; j < 4; ++j)
                    Cf[(size_t)(row0 + j) * N + col] = acc[m][n][j];
            } else {
                #pragma unroll
                for (int j = 0; j < 4; ++j)
                    Qo[(size_t)(row0 + j) * N + col] = (__bf16)acc[m][n][j];
            }
        }
    }
}

// in-place RoPE on bf16 [MROWS][nheads*HD]; cos/sin fp32 (B,S,HD), cos[d]==cos[d+64]
__global__ __launch_bounds__(256) void rope_kernel(__bf16* __restrict__ X,
                                                   const float* __restrict__ ct,
                                                   const float* __restrict__ st,
                                                   int nheads, int total) {
    int idx = blockIdx.x * 256 + threadIdx.x;
    if (idx >= total) return;
    int d  = idx & 63;
    int hh = (idx >> 6) % nheads;
    int m  = idx / (64 * nheads);
    __bf16* p = X + (size_t)m * (nheads * HD) + hh * HD;
    float c = ct[(size_t)m * HD + d];
    float s = st[(size_t)m * HD + d];
    float x1 = (float)p[d], x2 = (float)p[d + 64];
    p[d]      = (__bf16)(x1 * c - x2 * s);
    p[d + 64] = (__bf16)(x2 * c + x1 * s);
}

// flash attention, transposed-S, QB=128 (2 m-tiles/wave), unpaired 1024 blocks
// (longest-first), launch_bounds(256,3), LDS 42.75KB -> 3 resident blocks/CU.
// r10-proven inner loop: Pl[4][2] double-slot, SINGLE lgkm fence for both m-tiles
// (r15's per-mt fence serialized the softmax: 180us vs 110us). No QK^T setprio.
// RoPE-Q fused; exp2 softmax; defer-max THR=8; diagonal-only masking;
// KB=32 double-buffered, counted vmcnt(4), raw barriers.
__global__ __launch_bounds__(256, 3) void attn_kernel(const __bf16* __restrict__ Q,
                                                      const __bf16* __restrict__ K,
                                                      const __bf16* __restrict__ V,
                                                      __bf16* __restrict__ O,
                                                      const float* __restrict__ ct,
                                                      const float* __restrict__ st) {
    constexpr int QB = 128, KB = 32;
    constexpr int nqb = S_LEN / QB;              // 16
    const int cpx = gridDim.x >> 3;              // 128
    const int b0 = blockIdx.x;
    const int bid = (b0 & 7) * cpx + (b0 >> 3);
    const int qb  = nqb - 1 - (bid % nqb);       // longest blocks dispatch first
    const int h   = (bid / nqb) % NH;
    const int b   = bid / (nqb * NH);
    const int hkv = h >> 2;
    const int tid = threadIdx.x, lane = tid & 63, w = tid >> 6;
    const int lq = lane & 15, hi2 = lane >> 4;
    const int q0 = qb * QB, qrow_lo = q0 + w * 32;

    __shared__ __bf16 Ks[2][KB * HD];   // [32][128], phys slot s of row r = logical s^(r&7)
    __shared__ __bf16 Vt[2][HD * KB];   // [128][32], phys slot s of row d = logical s^(d&3)
    __shared__ __bf16 Pl[4][2][16][40]; // [wave][mt][q][kv]

    const int nkb = 4 * (qb + 1);

    auto stage = [&](int bb, int k0s) {          // 4 DMA issues/thread
        #pragma unroll
        for (int r = 0; r < 2; ++r) {
            int i = r * 256 + tid;
            {   int row = i >> 4, sl = i & 15, lsl = sl ^ (row & 7);
                gl_lds16(&K[((size_t)(b * S_LEN + k0s + row)) * (NKV * HD) + hkv * HD + lsl * 8],
                         &Ks[bb][i * 8]); }
            {   int d = i >> 2, sl = i & 3, lsl = sl ^ (d & 3);
                gl_lds16(&V[((size_t)((b * NKV + hkv) * HD + d)) * S_LEN + k0s + lsl * 8],
                         &Vt[bb][i * 8]); }
        }
    };

    const float c2 = 0.08838834764831843f * 1.4426950408889634f;  // scale * log2(e)

    // Q fragments: load raw Q, apply RoPE + exp2 prescale in-register.
    // chunk c holds d in [c*32+hi2*8, +8); rotation partner of chunk c is c+2.
    bf16x8 qf[2][4];
    #pragma unroll
    for (int mt = 0; mt < 2; ++mt) {
        int row = qrow_lo + mt * 16 + lq;
        const __bf16* qp = Q + ((size_t)(b * S_LEN + row)) * (NH * HD) + h * HD + hi2 * 8;
        const float* cp = ct + ((size_t)(b * S_LEN + row)) * HD + hi2 * 8;
        const float* sp = st + ((size_t)(b * S_LEN + row)) * HD + hi2 * 8;
        #pragma unroll
        for (int c = 0; c < 2; ++c) {
            bf16x8 lo = *(const bf16x8*)(qp + c * 32);
            bf16x8 hi = *(const bf16x8*)(qp + c * 32 + 64);
            f32x4 c0 = *(const f32x4*)(cp + c * 32);
            f32x4 c1 = *(const f32x4*)(cp + c * 32 + 4);
            f32x4 s0 = *(const f32x4*)(sp + c * 32);
            f32x4 s1 = *(const f32x4*)(sp + c * 32 + 4);
            bf16x8 rlo, rhi;
            #pragma unroll
            for (int e = 0; e < 8; ++e) {
                float cc = ((e < 4) ? c0[e] : c1[e - 4]) * c2;
                float ss = ((e < 4) ? s0[e] : s1[e - 4]) * c2;
                float xl = (float)lo[e], xh = (float)hi[e];
                rlo[e] = (__bf16)(xl * cc - xh * ss);
                rhi[e] = (__bf16)(xh * cc + xl * ss);
            }
            qf[mt][c]     = rlo;
            qf[mt][c + 2] = rhi;
        }
    }

    f32x4 o_acc[2][8] = {};
    float m_r[2] = {-1e30f, -1e30f}, l_r[2] = {0.f, 0.f};

    stage(0, 0);
    #pragma unroll 1
    for (int kb = 0; kb < nkb; ++kb) {
        int kn = (kb + 1 < nkb) ? kb + 1 : kb;   // clamp: keep vmcnt count uniform
        stage((kb + 1) & 1, kn * KB);
        asm volatile("s_waitcnt vmcnt(4)" ::: "memory");
        SBAR(); SCHEDB();
        const int cur = kb & 1;
        const int k0  = kb * KB;
        const __bf16* ks = &Ks[cur][0];
        const __bf16* vt = &Vt[cur][0];

        // S^T: 32 kv-rows x 16 q-cols per mt; kf shared across both m-tiles
        f32x4 sc[2][2] = {};
        #pragma unroll
        for (int t = 0; t < 2; ++t) {
            int krow = t * 16 + lq;
            #pragma unroll
            for (int c = 0; c < 4; ++c) {
                int psl = (c * 4 + hi2) ^ (krow & 7);
                bf16x8 kf = *(const bf16x8*)&ks[krow * HD + psl * 8];
                sc[0][t] = mfma16(kf, qf[0][c], sc[0][t]);
                sc[1][t] = mfma16(kf, qf[1][c], sc[1][t]);
            }
        }

        // mask + online softmax + P-write, per m-tile (single fence after both)
        #pragma unroll
        for (int mt = 0; mt < 2; ++mt) {
            int q_abs = qrow_lo + mt * 16 + lq;
            if (k0 + KB - 1 > qrow_lo + mt * 16) {   // diagonal tile: apply causal mask
                #pragma unroll
                for (int t = 0; t < 2; ++t)
                    #pragma unroll
                    for (int j = 0; j < 4; ++j) {
                        int kv_abs = k0 + t * 16 + hi2 * 4 + j;
                        if (kv_abs > q_abs) sc[mt][t][j] = -1e30f;
                    }
            }
            float pmax = fmaxf(
                fmaxf(fmaxf(sc[mt][0][0], sc[mt][0][1]), fmaxf(sc[mt][0][2], sc[mt][0][3])),
                fmaxf(fmaxf(sc[mt][1][0], sc[mt][1][1]), fmaxf(sc[mt][1][2], sc[mt][1][3])));
            pmax = fmaxf(pmax, __shfl_xor(pmax, 16));
            pmax = fmaxf(pmax, __shfl_xor(pmax, 32));
            if (!__all(pmax - m_r[mt] <= 8.0f)) {    // defer-max: rescale only when needed
                float mn = fmaxf(m_r[mt], pmax);
                float sf = __builtin_amdgcn_exp2f(m_r[mt] - mn);
                m_r[mt] = mn;
                l_r[mt] *= sf;
                #pragma unroll
                for (int dt = 0; dt < 8; ++dt)
                    #pragma unroll
                    for (int j = 0; j < 4; ++j) o_acc[mt][dt][j] *= sf;
            }
            float rs = 0.f;
            #pragma unroll
            for (int t = 0; t < 2; ++t)
                #pragma unroll
                for (int j = 0; j < 4; ++j) {
                    float p = __builtin_amdgcn_exp2f(sc[mt][t][j] - m_r[mt]);
                    sc[mt][t][j] = p;
                    rs += p;
                }
            rs += __shfl_xor(rs, 16);
            rs += __shfl_xor(rs, 32);
            l_r[mt] += rs;
            #pragma unroll
            for (int t = 0; t < 2; ++t) {
                bf16x4 pw;
                #pragma unroll
                for (int j = 0; j < 4; ++j) pw[j] = (__bf16)sc[mt][t][j];
                *(bf16x4*)&Pl[w][mt][lq][t * 16 + hi2 * 4] = pw;
            }
        }

        LGKM0(); SCHEDB();
        bf16x8 pf0 = *(const bf16x8*)&Pl[w][0][lq][hi2 * 8];
        bf16x8 pf1 = *(const bf16x8*)&Pl[w][1][lq][hi2 * 8];

        // PV: 8 d-tiles; vf shared across both m-tiles
        #pragma unroll
        for (int dt = 0; dt < 8; ++dt) {
            int vrow = dt * 16 + lq;
            int psl  = hi2 ^ (vrow & 3);
            bf16x8 vf = *(const bf16x8*)&vt[vrow * KB + psl * 8];
            o_acc[0][dt] = mfma16(vf, pf0, o_acc[0][dt]);
            o_acc[1][dt] = mfma16(vf, pf1, o_acc[1][dt]);
        }
        LGKM0(); SCHEDB();     // all cur ds_reads complete before next-iter DMA targets it
        SBAR(); SCHEDB();
    }

    #pragma unroll
    for (int mt = 0; mt < 2; ++mt) {
        float inv = 1.0f / l_r[mt];
        int q_abs = qrow_lo + mt * 16 + lq;
        __bf16* op = O + ((size_t)(b * S_LEN + q_abs)) * (NH * HD) + h * HD;
        #pragma unroll
        for (int dt = 0; dt < 8; ++dt) {
            bf16x4 t4;
            #pragma unroll
            for (int j = 0; j < 4; ++j) t4[j] = (__bf16)(o_acc[mt][dt][j] * inv);
            *(bf16x4*)&op[dt * 16 + hi2 * 4] = t4;
        }
    }
}

extern "C" void kernel_launch(void* const* d_in, const int* in_sizes, int n_in,
                              void* d_out, int out_size, void* d_ws, size_t ws_size,
                              hipStream_t stream) {
    const float* X  = (const float*)d_in[0];
    // d_in[1] = attention_mask: exactly causal; applied analytically in attn_kernel
    const float* ct = (const float*)d_in[2];
    const float* st = (const float*)d_in[3];
    const float* Wq = (const float*)d_in[4];
    const float* Wk = (const float*)d_in[5];
    const float* Wv = (const float*)d_in[6];
    const float* Wo = (const float*)d_in[7];
    float* out = (float*)d_out;

    const size_t MEL  = (size_t)MROWS * HIDDEN;      // 16.78M
    const size_t KVEL = (size_t)MROWS * (NKV * HD);  // 4.19M
    const int NQKV = NH * HD + 2 * NKV * HD;         // 6144

    // workspace (134.2 MB), dead-buffer aliasing.
    // ORDERING CONSTRAINT: Wob aliases Xb -> Wo conversion must run AFTER the
    // Q/KV projections consume Xb.
    __bf16* Wqkv = (__bf16*)d_ws;                   // [6144][4096] -> reused as Ab
    __bf16* Xb   = Wqkv + (size_t)NQKV * HIDDEN;    // [4096][4096] -> reused as Wob
    __bf16* Qb   = Xb + MEL;
    __bf16* Kb   = Qb + MEL;
    __bf16* VtG  = Kb + KVEL;
    __bf16* Ab   = Wqkv;
    __bf16* Wob  = Xb;

    dim3 blk(256);
    // fused conversions: X->Xb, Wq/Wk/Wv -> Wqkv (contiguous regions)
    const int cbM = (int)(MEL / 8 / 256);    // 8192 blocks per MEL segment
    const int cbK = (int)(KVEL / 8 / 256);   // 2048 blocks per KVEL segment
    hipLaunchKernelGGL(conv4, dim3(2 * cbM + 2 * cbK), blk, 0, stream,
                       X,  Xb, cbM,
                       Wq, Wqkv, cbM,
                       Wk, Wqkv + (size_t)HIDDEN * HIDDEN, cbK,
                       Wv, Wqkv + (size_t)(HIDDEN + NKV * HD) * HIDDEN);

    // Q projection: 4096x4096x4096, 256 blocks (exact machine fill); Qb is pre-RoPE
    hipLaunchKernelGGL((gemm256<0, 256>), dim3(256), dim3(512), 0, stream,
                       Xb, Wqkv, nullptr, Qb, nullptr, nullptr, NH * HD, HIDDEN, 16);
    // KV projection: 4096x2048x4096, BM=128 -> 256 blocks (exact fill)
    hipLaunchKernelGGL((gemm256<3, 128>), dim3(256), dim3(512), 0, stream,
                       Xb, Wqkv + (size_t)HIDDEN * HIDDEN, nullptr, nullptr, Kb, VtG,
                       2 * NKV * HD, HIDDEN, 8);

    // RoPE applied to K only (Q roped in-register inside attn)
    hipLaunchKernelGGL(rope_kernel, dim3((MROWS * NKV * 64) / 256), blk, 0, stream,
                       Kb, ct, st, NKV, MROWS * NKV * 64);

    // Wo conversion into Xb's slot (X dead only after the projections above)
    hipLaunchKernelGGL(conv_f32_bf16, dim3(cbM), blk, 0, stream, Wo, Wob, (int)(MEL / 8));

    // attention: 16 qb x 32 heads x 2 batch = 1024 blocks, longest-first
    hipLaunchKernelGGL(attn_kernel, dim3(1024), blk, 0, stream, Qb, Kb, VtG, Ab, ct, st);

    // O projection: 4096x4096x4096 -> fp32 out, 256 blocks (exact fill)
    hipLaunchKernelGGL((gemm256<1, 256>), dim3(256), dim3(512), 0, stream,
                       Ab, Wob, out, nullptr, nullptr, nullptr, HIDDEN, HIDDEN, 16);
}

// Round 17
// 553.763 us; speedup vs baseline: 1.7200x; 1.0650x over previous
//
#include <hip/hip_runtime.h>
#include <hip/hip_bf16.h>
#include <cstdint>

#define S_LEN 2048
#define HIDDEN 4096
#define NH 32
#define NKV 8
#define HD 128
#define BATCH 2
#define MROWS (BATCH * S_LEN)   // 4096

typedef float f32x4 __attribute__((ext_vector_type(4)));
typedef __bf16 bf16x8 __attribute__((ext_vector_type(8)));
typedef __bf16 bf16x4 __attribute__((ext_vector_type(4)));

static __device__ inline f32x4 mfma16(bf16x8 a, bf16x8 b, f32x4 c) {
    return __builtin_amdgcn_mfma_f32_16x16x32_bf16(a, b, c, 0, 0, 0);
}

// async global->LDS, 16B per lane; LDS dest = wave-uniform base + lane*16
static __device__ inline void gl_lds16(const __bf16* g, __bf16* l) {
    __builtin_amdgcn_global_load_lds(
        (const __attribute__((address_space(1))) void*)g,
        (__attribute__((address_space(3))) void*)l, 16, 0, 0);
}

#define LGKM0()  asm volatile("s_waitcnt lgkmcnt(0)" ::: "memory")
#define SCHEDB() __builtin_amdgcn_sched_barrier(0)
#define SBAR()   __builtin_amdgcn_s_barrier()

static __device__ inline void conv8(const float* src, __bf16* dst, int i) {
    const float4* p = (const float4*)src + (size_t)i * 2;
    float4 a = p[0], b = p[1];
    bf16x8 v;
    v[0] = (__bf16)a.x; v[1] = (__bf16)a.y; v[2] = (__bf16)a.z; v[3] = (__bf16)a.w;
    v[4] = (__bf16)b.x; v[5] = (__bf16)b.y; v[6] = (__bf16)b.z; v[7] = (__bf16)b.w;
    ((bf16x8*)dst)[i] = v;
}

// fp32 -> bf16 bulk convert, single segment
__global__ __launch_bounds__(256) void conv_f32_bf16(const float* __restrict__ in,
                                                     __bf16* __restrict__ out, int n8) {
    int i = blockIdx.x * 256 + threadIdx.x;
    if (i >= n8) return;
    conv8(in, out, i);
}

// fused 4-segment fp32 -> bf16 convert (block-uniform segment selection)
__global__ __launch_bounds__(256) void conv4(const float* __restrict__ s0, __bf16* __restrict__ d0, int b0,
                                             const float* __restrict__ s1, __bf16* __restrict__ d1, int b1,
                                             const float* __restrict__ s2, __bf16* __restrict__ d2, int b2,
                                             const float* __restrict__ s3, __bf16* __restrict__ d3) {
    int blk = blockIdx.x;
    const float* s; __bf16* d; int base;
    if (blk < b0)                { s = s0; d = d0; base = blk; }
    else if (blk < b0 + b1)      { s = s1; d = d1; base = blk - b0; }
    else if (blk < b0 + b1 + b2) { s = s2; d = d2; base = blk - b0 - b1; }
    else                         { s = s3; d = d3; base = blk - b0 - b1 - b2; }
    conv8(s, d, base * 256 + threadIdx.x);
}

// BM x 256 x K GEMM, C[m,n] = sum_k A[m,k]*B[n,k], bf16 in, 8 waves (512 thr).
// Round-7 proven structure: double-buffered LDS, ^(row&7) 16B-slot XOR swizzle,
// 4 phases/K-tile, counted vmcnt once per K-tile, raw barriers, setprio MFMA.
// MODE 0: bf16 C flat. MODE 1: fp32 C flat. MODE 3: KV routing (K flat / V transposed).
template<int MODE, int BM>
__global__ __launch_bounds__(512, 2) void gemm256(const __bf16* __restrict__ A,
                                                  const __bf16* __restrict__ B,
                                                  float* __restrict__ Cf,
                                                  __bf16* __restrict__ Qo,
                                                  __bf16* __restrict__ Ko,
                                                  __bf16* __restrict__ Vo,
                                                  int N, int K, int nbx) {
    constexpr int MF = BM / 32;
    constexpr int MH = BM / 64;
    __shared__ __bf16 As[2][BM * 64];
    __shared__ __bf16 Bs[2][256 * 64];
    const int tid = threadIdx.x, lane = tid & 63;
    const int lq = lane & 15, hi2 = lane >> 4;
    const int wv = tid >> 6;
    const int wr = wv >> 2, wc = wv & 3;

    const int cpx = gridDim.x >> 3;
    const int bid = blockIdx.x;
    const int swz = (bid & 7) * cpx + (bid >> 3);
    const int bx = swz % nbx, by = swz / nbx;
    const int brow = by * BM, bcol = bx * 256;

    f32x4 acc[MF][4] = {};
    bf16x8 af[MH][2], bfr[2][2];
    const int NT = K >> 6;

    auto stageA = [&](int bb, int kt, int roff) {
        #pragma unroll
        for (int r = 0; r < 2; ++r) {
            int i = r * 512 + tid;
            int row = i >> 3, sl = i & 7, lsl = sl ^ (row & 7);
            gl_lds16(A + (size_t)(brow + roff + row) * K + kt * 64 + lsl * 8,
                     &As[bb][roff * 64 + i * 8]);
        }
    };
    auto stageB = [&](int bb, int kt, int roff) {
        #pragma unroll
        for (int r = 0; r < 2; ++r) {
            int i = r * 512 + tid;
            int row = i >> 3, sl = i & 7, lsl = sl ^ (row & 7);
            gl_lds16(B + (size_t)(bcol + roff + row) * K + kt * 64 + lsl * 8,
                     &Bs[bb][roff * 64 + i * 8]);
        }
    };
    auto loadA = [&](int bb, int mq) {
        #pragma unroll
        for (int mi = 0; mi < MH; ++mi) {
            int row = wr * (BM / 2) + (mq * MH + mi) * 16 + lq;
            #pragma unroll
            for (int kk = 0; kk < 2; ++kk) {
                int lsl = (kk * 4 + hi2) ^ (row & 7);
                af[mi][kk] = *(const bf16x8*)&As[bb][row * 64 + lsl * 8];
            }
        }
    };
    auto loadB = [&](int bb, int nq) {
        #pragma unroll
        for (int ni = 0; ni < 2; ++ni) {
            int row = wc * 64 + (nq * 2 + ni) * 16 + lq;
            #pragma unroll
            for (int kk = 0; kk < 2; ++kk) {
                int lsl = (kk * 4 + hi2) ^ (row & 7);
                bfr[ni][kk] = *(const bf16x8*)&Bs[bb][row * 64 + lsl * 8];
            }
        }
    };
    auto mmaq = [&](int mq, int nq) {
        __builtin_amdgcn_s_setprio(1);
        #pragma unroll
        for (int kk = 0; kk < 2; ++kk)
            #pragma unroll
            for (int mi = 0; mi < MH; ++mi)
                #pragma unroll
                for (int ni = 0; ni < 2; ++ni)
                    acc[mq * MH + mi][nq * 2 + ni] =
                        mfma16(af[mi][kk], bfr[ni][kk], acc[mq * MH + mi][nq * 2 + ni]);
        __builtin_amdgcn_s_setprio(0);
    };

    stageA(0, 0, 0);
    if constexpr (BM == 256) stageA(0, 0, 128);
    stageB(0, 0, 0);
    stageB(0, 0, 128);

    for (int t = 0; t < NT; ++t) {
        const int cur = t & 1, nxt = cur ^ 1;
        const int tn = (t + 1 < NT) ? t + 1 : NT - 1;
        stageA(nxt, tn, 0);
        if constexpr (BM == 256) stageA(nxt, tn, 128);
        stageB(nxt, tn, 0);
        if constexpr (BM == 256) { asm volatile("s_waitcnt vmcnt(6)" ::: "memory"); }
        else                     { asm volatile("s_waitcnt vmcnt(4)" ::: "memory"); }
        SBAR(); SCHEDB();
        loadA(cur, 0); loadB(cur, 0);
        LGKM0(); SCHEDB();
        mmaq(0, 0);
        SBAR(); SCHEDB();
        loadB(cur, 1);
        stageB(nxt, tn, 128);
        SBAR(); SCHEDB();
        LGKM0(); SCHEDB();
        mmaq(0, 1);
        SBAR(); SCHEDB();
        loadA(cur, 1);
        SBAR(); SCHEDB();
        LGKM0(); SCHEDB();
        mmaq(1, 1);
        SBAR(); SCHEDB();
        loadB(cur, 0);
        SBAR(); SCHEDB();
        LGKM0(); SCHEDB();
        mmaq(1, 0);
        SBAR(); SCHEDB();
    }

    #pragma unroll
    for (int m = 0; m < MF; ++m) {
        #pragma unroll
        for (int n = 0; n < 4; ++n) {
            int row0 = brow + wr * (BM / 2) + m * 16 + (hi2 << 2);
            int col  = bcol + wc * 64 + n * 16 + lq;
            if constexpr (MODE == 3) {
                if (col < NKV * HD) {
                    #pragma unroll
                    for (int j = 0; j < 4; ++j)
                        Ko[(size_t)(row0 + j) * (NKV * HD) + col] = (__bf16)acc[m][n][j];
                } else {
                    int c2 = col - NKV * HD;
                    int hkv = c2 >> 7, d = c2 & (HD - 1);
                    int bb2 = row0 >> 11, s = row0 & (S_LEN - 1);
                    bf16x4 t4;
                    #pragma unroll
                    for (int j = 0; j < 4; ++j) t4[j] = (__bf16)acc[m][n][j];
                    *(bf16x4*)&Vo[((size_t)((bb2 * NKV + hkv) * HD + d)) * S_LEN + s] = t4;
                }
            } else if constexpr (MODE == 1) {
                #pragma unroll
                for (int j = 0; j < 4; ++j)
                    Cf[(size_t)(row0 + j) * N + col] = acc[m][n][j];
            } else {
                #pragma unroll
                for (int j = 0; j < 4; ++j)
                    Qo[(size_t)(row0 + j) * N + col] = (__bf16)acc[m][n][j];
            }
        }
    }
}

// in-place RoPE on bf16 [MROWS][nheads*HD]; cos/sin fp32 (B,S,HD), cos[d]==cos[d+64]
__global__ __launch_bounds__(256) void rope_kernel(__bf16* __restrict__ X,
                                                   const float* __restrict__ ct,
                                                   const float* __restrict__ st,
                                                   int nheads, int total) {
    int idx = blockIdx.x * 256 + threadIdx.x;
    if (idx >= total) return;
    int d  = idx & 63;
    int hh = (idx >> 6) % nheads;
    int m  = idx / (64 * nheads);
    __bf16* p = X + (size_t)m * (nheads * HD) + hh * HD;
    float c = ct[(size_t)m * HD + d];
    float s = st[(size_t)m * HD + d];
    float x1 = (float)p[d], x2 = (float)p[d + 64];
    p[d]      = (__bf16)(x1 * c - x2 * s);
    p[d + 64] = (__bf16)(x2 * c + x1 * s);
}

// flash attention, transposed-S, PAIRED q-tiles (r10-proven grid: 512 blocks x
// uniform 68 iters = perfect static fill; r15/r16's unpaired 1024 grid lost 60us
// to drain imbalance). QB=128, KB=32 double-buffered, counted vmcnt(4), raw
// barriers, Pl[4][2] single fence. RoPE-Q fused; exp2 softmax; defer-max THR=8;
// diagonal-only masking. NEW vs r10: l-sum reduction deferred to epilogue
// (per-lane partial l_r; rescale is wave-uniform so partials stay consistent)
// -- saves 2 ds_swizzle (DS pipe) per mt per iter on the LDS-bound loop.
__global__ __launch_bounds__(256, 3) void attn_kernel(const __bf16* __restrict__ Q,
                                                      const __bf16* __restrict__ K,
                                                      const __bf16* __restrict__ V,
                                                      __bf16* __restrict__ O,
                                                      const float* __restrict__ ct,
                                                      const float* __restrict__ st) {
    constexpr int QB = 128, KB = 32;
    constexpr int nqb = S_LEN / QB;              // 16
    const int cpx = gridDim.x >> 3;              // 64
    const int b0 = blockIdx.x;
    const int bid = (b0 & 7) * cpx + (b0 >> 3);
    const int pair = bid & 7;
    const int h    = (bid >> 3) & (NH - 1);
    const int b    = bid >> 8;
    const int hkv = h >> 2;
    const int tid = threadIdx.x, lane = tid & 63, w = tid >> 6;
    const int lq = lane & 15, hi2 = lane >> 4;

    __shared__ __bf16 Ks[2][KB * HD];   // [32][128], phys slot s of row r = logical s^(r&7)
    __shared__ __bf16 Vt[2][HD * KB];   // [128][32], phys slot s of row d = logical s^(d&3)
    __shared__ __bf16 Pl[4][2][16][40]; // [wave][mt][q][kv]

    const int qbA = nqb - 1 - pair;      // long pass first
    const int nkbA = 4 * (qbA + 1);
    const int T = nkbA + 4 * (pair + 1); // = 68 for all blocks

    auto stage = [&](int bb, int k0s) {          // 4 DMA issues/thread
        #pragma unroll
        for (int r = 0; r < 2; ++r) {
            int i = r * 256 + tid;
            {   int row = i >> 4, sl = i & 15, lsl = sl ^ (row & 7);
                gl_lds16(&K[((size_t)(b * S_LEN + k0s + row)) * (NKV * HD) + hkv * HD + lsl * 8],
                         &Ks[bb][i * 8]); }
            {   int d = i >> 2, sl = i & 3, lsl = sl ^ (d & 3);
                gl_lds16(&V[((size_t)((b * NKV + hkv) * HD + d)) * S_LEN + k0s + lsl * 8],
                         &Vt[bb][i * 8]); }
        }
    };

    const float c2 = 0.08838834764831843f * 1.4426950408889634f;  // scale * log2(e)

    stage(0, 0);
    int tt = 0;
    #pragma unroll 1
    for (int pass = 0; pass < 2; ++pass) {
        const int qb = pass ? pair : qbA;
        const int q0 = qb * QB, qrow_lo = q0 + w * 32;
        const int nkb = 4 * (qb + 1);

        // Q fragments: load raw Q, apply RoPE + exp2 prescale in-register.
        // chunk c holds d in [c*32+hi2*8, +8); rotation partner of chunk c is c+2.
        bf16x8 qf[2][4];
        #pragma unroll
        for (int mt = 0; mt < 2; ++mt) {
            int row = qrow_lo + mt * 16 + lq;
            const __bf16* qp = Q + ((size_t)(b * S_LEN + row)) * (NH * HD) + h * HD + hi2 * 8;
            const float* cp = ct + ((size_t)(b * S_LEN + row)) * HD + hi2 * 8;
            const float* sp = st + ((size_t)(b * S_LEN + row)) * HD + hi2 * 8;
            #pragma unroll
            for (int c = 0; c < 2; ++c) {
                bf16x8 lo = *(const bf16x8*)(qp + c * 32);
                bf16x8 hi = *(const bf16x8*)(qp + c * 32 + 64);
                f32x4 c0 = *(const f32x4*)(cp + c * 32);
                f32x4 c1 = *(const f32x4*)(cp + c * 32 + 4);
                f32x4 s0 = *(const f32x4*)(sp + c * 32);
                f32x4 s1 = *(const f32x4*)(sp + c * 32 + 4);
                bf16x8 rlo, rhi;
                #pragma unroll
                for (int e = 0; e < 8; ++e) {
                    float cc = ((e < 4) ? c0[e] : c1[e - 4]) * c2;
                    float ss = ((e < 4) ? s0[e] : s1[e - 4]) * c2;
                    float xl = (float)lo[e], xh = (float)hi[e];
                    rlo[e] = (__bf16)(xl * cc - xh * ss);
                    rhi[e] = (__bf16)(xh * cc + xl * ss);
                }
                qf[mt][c]     = rlo;
                qf[mt][c + 2] = rhi;
            }
        }

        f32x4 o_acc[2][8] = {};
        float m_r[2] = {-1e30f, -1e30f}, l_r[2] = {0.f, 0.f};  // l_r = per-lane PARTIAL

        #pragma unroll 1
        for (int kb = 0; kb < nkb; ++kb, ++tt) {
            int tn = (tt + 1 < T) ? tt + 1 : T - 1;
            int k0n = (tn < nkbA ? tn : tn - nkbA) * KB;
            stage((tt + 1) & 1, k0n);
            asm volatile("s_waitcnt vmcnt(4)" ::: "memory");
            SBAR(); SCHEDB();
            const int cur = tt & 1;
            const int k0  = kb * KB;
            const __bf16* ks = &Ks[cur][0];
            const __bf16* vt = &Vt[cur][0];

            // S^T: 32 kv-rows x 16 q-cols per mt; kf shared across both m-tiles
            f32x4 sc[2][2] = {};
            #pragma unroll
            for (int t = 0; t < 2; ++t) {
                int krow = t * 16 + lq;
                #pragma unroll
                for (int c = 0; c < 4; ++c) {
                    int psl = (c * 4 + hi2) ^ (krow & 7);
                    bf16x8 kf = *(const bf16x8*)&ks[krow * HD + psl * 8];
                    sc[0][t] = mfma16(kf, qf[0][c], sc[0][t]);
                    sc[1][t] = mfma16(kf, qf[1][c], sc[1][t]);
                }
            }

            // mask + online softmax + P-write, per m-tile (single fence after both)
            #pragma unroll
            for (int mt = 0; mt < 2; ++mt) {
                int q_abs = qrow_lo + mt * 16 + lq;
                if (k0 + KB - 1 > qrow_lo + mt * 16) {   // diagonal tile: causal mask
                    #pragma unroll
                    for (int t = 0; t < 2; ++t)
                        #pragma unroll
                        for (int j = 0; j < 4; ++j) {
                            int kv_abs = k0 + t * 16 + hi2 * 4 + j;
                            if (kv_abs > q_abs) sc[mt][t][j] = -1e30f;
                        }
                }
                float pmax = fmaxf(
                    fmaxf(fmaxf(sc[mt][0][0], sc[mt][0][1]), fmaxf(sc[mt][0][2], sc[mt][0][3])),
                    fmaxf(fmaxf(sc[mt][1][0], sc[mt][1][1]), fmaxf(sc[mt][1][2], sc[mt][1][3])));
                pmax = fmaxf(pmax, __shfl_xor(pmax, 16));
                pmax = fmaxf(pmax, __shfl_xor(pmax, 32));
                if (!__all(pmax - m_r[mt] <= 8.0f)) {    // defer-max (wave-uniform branch)
                    float mn = fmaxf(m_r[mt], pmax);
                    float sf = __builtin_amdgcn_exp2f(m_r[mt] - mn);
                    m_r[mt] = mn;
                    l_r[mt] *= sf;                       // partial scaled consistently
                    #pragma unroll
                    for (int dt = 0; dt < 8; ++dt)
                        #pragma unroll
                        for (int j = 0; j < 4; ++j) o_acc[mt][dt][j] *= sf;
                }
                float rs = 0.f;
                #pragma unroll
                for (int t = 0; t < 2; ++t)
                    #pragma unroll
                    for (int j = 0; j < 4; ++j) {
                        float p = __builtin_amdgcn_exp2f(sc[mt][t][j] - m_r[mt]);
                        sc[mt][t][j] = p;
                        rs += p;
                    }
                l_r[mt] += rs;                           // deferred: no per-iter shuffles
                #pragma unroll
                for (int t = 0; t < 2; ++t) {
                    bf16x4 pw;
                    #pragma unroll
                    for (int j = 0; j < 4; ++j) pw[j] = (__bf16)sc[mt][t][j];
                    *(bf16x4*)&Pl[w][mt][lq][t * 16 + hi2 * 4] = pw;
                }
            }

            LGKM0(); SCHEDB();
            bf16x8 pf0 = *(const bf16x8*)&Pl[w][0][lq][hi2 * 8];
            bf16x8 pf1 = *(const bf16x8*)&Pl[w][1][lq][hi2 * 8];

            // PV: 8 d-tiles; vf shared across both m-tiles
            #pragma unroll
            for (int dt = 0; dt < 8; ++dt) {
                int vrow = dt * 16 + lq;
                int psl  = hi2 ^ (vrow & 3);
                bf16x8 vf = *(const bf16x8*)&vt[vrow * KB + psl * 8];
                o_acc[0][dt] = mfma16(vf, pf0, o_acc[0][dt]);
                o_acc[1][dt] = mfma16(vf, pf1, o_acc[1][dt]);
            }
            LGKM0(); SCHEDB();     // all cur ds_reads complete before next-iter DMA
            SBAR(); SCHEDB();
        }

        #pragma unroll
        for (int mt = 0; mt < 2; ++mt) {
            float lsum = l_r[mt];                        // reduce partials now
            lsum += __shfl_xor(lsum, 16);
            lsum += __shfl_xor(lsum, 32);
            float inv = 1.0f / lsum;
            int q_abs = qrow_lo + mt * 16 + lq;
            __bf16* op = O + ((size_t)(b * S_LEN + q_abs)) * (NH * HD) + h * HD;
            #pragma unroll
            for (int dt = 0; dt < 8; ++dt) {
                bf16x4 t4;
                #pragma unroll
                for (int j = 0; j < 4; ++j) t4[j] = (__bf16)(o_acc[mt][dt][j] * inv);
                *(bf16x4*)&op[dt * 16 + hi2 * 4] = t4;
            }
        }
    }
}

extern "C" void kernel_launch(void* const* d_in, const int* in_sizes, int n_in,
                              void* d_out, int out_size, void* d_ws, size_t ws_size,
                              hipStream_t stream) {
    const float* X  = (const float*)d_in[0];
    // d_in[1] = attention_mask: exactly causal; applied analytically in attn_kernel
    const float* ct = (const float*)d_in[2];
    const float* st = (const float*)d_in[3];
    const float* Wq = (const float*)d_in[4];
    const float* Wk = (const float*)d_in[5];
    const float* Wv = (const float*)d_in[6];
    const float* Wo = (const float*)d_in[7];
    float* out = (float*)d_out;

    const size_t MEL  = (size_t)MROWS * HIDDEN;      // 16.78M
    const size_t KVEL = (size_t)MROWS * (NKV * HD);  // 4.19M
    const int NQKV = NH * HD + 2 * NKV * HD;         // 6144

    // workspace (134.2 MB), dead-buffer aliasing.
    // ORDERING CONSTRAINT: Wob aliases Xb -> Wo conversion must run AFTER the
    // Q/KV projections consume Xb.
    __bf16* Wqkv = (__bf16*)d_ws;                   // [6144][4096] -> reused as Ab
    __bf16* Xb   = Wqkv + (size_t)NQKV * HIDDEN;    // [4096][4096] -> reused as Wob
    __bf16* Qb   = Xb + MEL;
    __bf16* Kb   = Qb + MEL;
    __bf16* VtG  = Kb + KVEL;
    __bf16* Ab   = Wqkv;
    __bf16* Wob  = Xb;

    dim3 blk(256);
    // fused conversions: X->Xb, Wq/Wk/Wv -> Wqkv (contiguous regions)
    const int cbM = (int)(MEL / 8 / 256);    // 8192 blocks per MEL segment
    const int cbK = (int)(KVEL / 8 / 256);   // 2048 blocks per KVEL segment
    hipLaunchKernelGGL(conv4, dim3(2 * cbM + 2 * cbK), blk, 0, stream,
                       X,  Xb, cbM,
                       Wq, Wqkv, cbM,
                       Wk, Wqkv + (size_t)HIDDEN * HIDDEN, cbK,
                       Wv, Wqkv + (size_t)(HIDDEN + NKV * HD) * HIDDEN);

    // Q projection: 4096x4096x4096, 256 blocks (exact machine fill); Qb is pre-RoPE
    hipLaunchKernelGGL((gemm256<0, 256>), dim3(256), dim3(512), 0, stream,
                       Xb, Wqkv, nullptr, Qb, nullptr, nullptr, NH * HD, HIDDEN, 16);
    // KV projection: 4096x2048x4096, BM=128 -> 256 blocks (exact fill)
    hipLaunchKernelGGL((gemm256<3, 128>), dim3(256), dim3(512), 0, stream,
                       Xb, Wqkv + (size_t)HIDDEN * HIDDEN, nullptr, nullptr, Kb, VtG,
                       2 * NKV * HD, HIDDEN, 8);

    // RoPE applied to K only (Q roped in-register inside attn)
    hipLaunchKernelGGL(rope_kernel, dim3((MROWS * NKV * 64) / 256), blk, 0, stream,
                       Kb, ct, st, NKV, MROWS * NKV * 64);

    // Wo conversion into Xb's slot (X dead only after the projections above)
    hipLaunchKernelGGL(conv_f32_bf16, dim3(cbM), blk, 0, stream, Wo, Wob, (int)(MEL / 8));

    // attention: 8 pairs x 32 heads x 2 batch = 512 uniform blocks (68 iters each)
    hipLaunchKernelGGL(attn_kernel, dim3(512), blk, 0, stream, Qb, Kb, VtG, Ab, ct, st);

    // O projection: 4096x4096x4096 -> fp32 out, 256 blocks (exact fill)
    hipLaunchKernelGGL((gemm256<1, 256>), dim3(256), dim3(512), 0, stream,
                       Ab, Wob, out, nullptr, nullptr, nullptr, HIDDEN, HIDDEN, 16);
}

// Round 18
// 550.194 us; speedup vs baseline: 1.7311x; 1.0065x over previous
//
#include <hip/hip_runtime.h>
#include <hip/hip_bf16.h>
#include <cstdint>

#define S_LEN 2048
#define HIDDEN 4096
#define NH 32
#define NKV 8
#define HD 128
#define BATCH 2
#define MROWS (BATCH * S_LEN)   // 4096

typedef float f32x4 __attribute__((ext_vector_type(4)));
typedef __bf16 bf16x8 __attribute__((ext_vector_type(8)));
typedef __bf16 bf16x4 __attribute__((ext_vector_type(4)));

static __device__ inline f32x4 mfma16(bf16x8 a, bf16x8 b, f32x4 c) {
    return __builtin_amdgcn_mfma_f32_16x16x32_bf16(a, b, c, 0, 0, 0);
}

// async global->LDS, 16B per lane; LDS dest = wave-uniform base + lane*16
static __device__ inline void gl_lds16(const __bf16* g, __bf16* l) {
    __builtin_amdgcn_global_load_lds(
        (const __attribute__((address_space(1))) void*)g,
        (__attribute__((address_space(3))) void*)l, 16, 0, 0);
}

#define LGKM0()  asm volatile("s_waitcnt lgkmcnt(0)" ::: "memory")
#define SCHEDB() __builtin_amdgcn_sched_barrier(0)
#define SBAR()   __builtin_amdgcn_s_barrier()

static __device__ inline void conv8(const float* src, __bf16* dst, int i) {
    const float4* p = (const float4*)src + (size_t)i * 2;
    float4 a = p[0], b = p[1];
    bf16x8 v;
    v[0] = (__bf16)a.x; v[1] = (__bf16)a.y; v[2] = (__bf16)a.z; v[3] = (__bf16)a.w;
    v[4] = (__bf16)b.x; v[5] = (__bf16)b.y; v[6] = (__bf16)b.z; v[7] = (__bf16)b.w;
    ((bf16x8*)dst)[i] = v;
}

// fused 4-segment fp32 -> bf16 convert (block-uniform segment selection)
__global__ __launch_bounds__(256) void conv4(const float* __restrict__ s0, __bf16* __restrict__ d0, int b0,
                                             const float* __restrict__ s1, __bf16* __restrict__ d1, int b1,
                                             const float* __restrict__ s2, __bf16* __restrict__ d2, int b2,
                                             const float* __restrict__ s3, __bf16* __restrict__ d3) {
    int blk = blockIdx.x;
    const float* s; __bf16* d; int base;
    if (blk < b0)                { s = s0; d = d0; base = blk; }
    else if (blk < b0 + b1)      { s = s1; d = d1; base = blk - b0; }
    else if (blk < b0 + b1 + b2) { s = s2; d = d2; base = blk - b0 - b1; }
    else                         { s = s3; d = d3; base = blk - b0 - b1 - b2; }
    conv8(s, d, base * 256 + threadIdx.x);
}

// fused: blocks [0,ropeB) apply RoPE-K in place; blocks [ropeB, ropeB+convB)
// convert Wo fp32->bf16. Independent buffers; block-uniform branch.
__global__ __launch_bounds__(256) void rope_conv(__bf16* __restrict__ Kb,
                                                 const float* __restrict__ ct,
                                                 const float* __restrict__ st,
                                                 int ropeB,
                                                 const float* __restrict__ Wo,
                                                 __bf16* __restrict__ Wob) {
    int blk = blockIdx.x;
    if (blk < ropeB) {
        int idx = blk * 256 + threadIdx.x;          // RoPE on [MROWS][NKV*HD]
        int d  = idx & 63;
        int hh = (idx >> 6) % NKV;
        int m  = idx / (64 * NKV);
        __bf16* p = Kb + (size_t)m * (NKV * HD) + hh * HD;
        float c = ct[(size_t)m * HD + d];
        float s = st[(size_t)m * HD + d];
        float x1 = (float)p[d], x2 = (float)p[d + 64];
        p[d]      = (__bf16)(x1 * c - x2 * s);
        p[d + 64] = (__bf16)(x2 * c + x1 * s);
    } else {
        conv8(Wo, Wob, (blk - ropeB) * 256 + threadIdx.x);
    }
}

// BM x 256 x K GEMM, C[m,n] = sum_k A[m,k]*B[n,k], bf16 in, 8 waves (512 thr).
// Round-7 proven structure: double-buffered LDS, ^(row&7) 16B-slot XOR swizzle,
// 4 phases/K-tile, counted vmcnt once per K-tile, raw barriers, setprio MFMA.
// MODE 0: bf16 C flat. MODE 1: fp32 C flat. MODE 3: KV routing (K flat / V transposed).
template<int MODE, int BM>
__global__ __launch_bounds__(512, 2) void gemm256(const __bf16* __restrict__ A,
                                                  const __bf16* __restrict__ B,
                                                  float* __restrict__ Cf,
                                                  __bf16* __restrict__ Qo,
                                                  __bf16* __restrict__ Ko,
                                                  __bf16* __restrict__ Vo,
                                                  int N, int K, int nbx) {
    constexpr int MF = BM / 32;
    constexpr int MH = BM / 64;
    __shared__ __bf16 As[2][BM * 64];
    __shared__ __bf16 Bs[2][256 * 64];
    const int tid = threadIdx.x, lane = tid & 63;
    const int lq = lane & 15, hi2 = lane >> 4;
    const int wv = tid >> 6;
    const int wr = wv >> 2, wc = wv & 3;

    const int cpx = gridDim.x >> 3;
    const int bid = blockIdx.x;
    const int swz = (bid & 7) * cpx + (bid >> 3);
    const int bx = swz % nbx, by = swz / nbx;
    const int brow = by * BM, bcol = bx * 256;

    f32x4 acc[MF][4] = {};
    bf16x8 af[MH][2], bfr[2][2];
    const int NT = K >> 6;

    auto stageA = [&](int bb, int kt, int roff) {
        #pragma unroll
        for (int r = 0; r < 2; ++r) {
            int i = r * 512 + tid;
            int row = i >> 3, sl = i & 7, lsl = sl ^ (row & 7);
            gl_lds16(A + (size_t)(brow + roff + row) * K + kt * 64 + lsl * 8,
                     &As[bb][roff * 64 + i * 8]);
        }
    };
    auto stageB = [&](int bb, int kt, int roff) {
        #pragma unroll
        for (int r = 0; r < 2; ++r) {
            int i = r * 512 + tid;
            int row = i >> 3, sl = i & 7, lsl = sl ^ (row & 7);
            gl_lds16(B + (size_t)(bcol + roff + row) * K + kt * 64 + lsl * 8,
                     &Bs[bb][roff * 64 + i * 8]);
        }
    };
    auto loadA = [&](int bb, int mq) {
        #pragma unroll
        for (int mi = 0; mi < MH; ++mi) {
            int row = wr * (BM / 2) + (mq * MH + mi) * 16 + lq;
            #pragma unroll
            for (int kk = 0; kk < 2; ++kk) {
                int lsl = (kk * 4 + hi2) ^ (row & 7);
                af[mi][kk] = *(const bf16x8*)&As[bb][row * 64 + lsl * 8];
            }
        }
    };
    auto loadB = [&](int bb, int nq) {
        #pragma unroll
        for (int ni = 0; ni < 2; ++ni) {
            int row = wc * 64 + (nq * 2 + ni) * 16 + lq;
            #pragma unroll
            for (int kk = 0; kk < 2; ++kk) {
                int lsl = (kk * 4 + hi2) ^ (row & 7);
                bfr[ni][kk] = *(const bf16x8*)&Bs[bb][row * 64 + lsl * 8];
            }
        }
    };
    auto mmaq = [&](int mq, int nq) {
        __builtin_amdgcn_s_setprio(1);
        #pragma unroll
        for (int kk = 0; kk < 2; ++kk)
            #pragma unroll
            for (int mi = 0; mi < MH; ++mi)
                #pragma unroll
                for (int ni = 0; ni < 2; ++ni)
                    acc[mq * MH + mi][nq * 2 + ni] =
                        mfma16(af[mi][kk], bfr[ni][kk], acc[mq * MH + mi][nq * 2 + ni]);
        __builtin_amdgcn_s_setprio(0);
    };

    stageA(0, 0, 0);
    if constexpr (BM == 256) stageA(0, 0, 128);
    stageB(0, 0, 0);
    stageB(0, 0, 128);

    for (int t = 0; t < NT; ++t) {
        const int cur = t & 1, nxt = cur ^ 1;
        const int tn = (t + 1 < NT) ? t + 1 : NT - 1;
        stageA(nxt, tn, 0);
        if constexpr (BM == 256) stageA(nxt, tn, 128);
        stageB(nxt, tn, 0);
        if constexpr (BM == 256) { asm volatile("s_waitcnt vmcnt(6)" ::: "memory"); }
        else                     { asm volatile("s_waitcnt vmcnt(4)" ::: "memory"); }
        SBAR(); SCHEDB();
        loadA(cur, 0); loadB(cur, 0);
        LGKM0(); SCHEDB();
        mmaq(0, 0);
        SBAR(); SCHEDB();
        loadB(cur, 1);
        stageB(nxt, tn, 128);
        SBAR(); SCHEDB();
        LGKM0(); SCHEDB();
        mmaq(0, 1);
        SBAR(); SCHEDB();
        loadA(cur, 1);
        SBAR(); SCHEDB();
        LGKM0(); SCHEDB();
        mmaq(1, 1);
        SBAR(); SCHEDB();
        loadB(cur, 0);
        SBAR(); SCHEDB();
        LGKM0(); SCHEDB();
        mmaq(1, 0);
        SBAR(); SCHEDB();
    }

    #pragma unroll
    for (int m = 0; m < MF; ++m) {
        #pragma unroll
        for (int n = 0; n < 4; ++n) {
            int row0 = brow + wr * (BM / 2) + m * 16 + (hi2 << 2);
            int col  = bcol + wc * 64 + n * 16 + lq;
            if constexpr (MODE == 3) {
                if (col < NKV * HD) {
                    #pragma unroll
                    for (int j = 0; j < 4; ++j)
                        Ko[(size_t)(row0 + j) * (NKV * HD) + col] = (__bf16)acc[m][n][j];
                } else {
                    int c2 = col - NKV * HD;
                    int hkv = c2 >> 7, d = c2 & (HD - 1);
                    int bb2 = row0 >> 11, s = row0 & (S_LEN - 1);
                    bf16x4 t4;
                    #pragma unroll
                    for (int j = 0; j < 4; ++j) t4[j] = (__bf16)acc[m][n][j];
                    *(bf16x4*)&Vo[((size_t)((bb2 * NKV + hkv) * HD + d)) * S_LEN + s] = t4;
                }
            } else if constexpr (MODE == 1) {
                #pragma unroll
                for (int j = 0; j < 4; ++j)
                    Cf[(size_t)(row0 + j) * N + col] = acc[m][n][j];
            } else {
                #pragma unroll
                for (int j = 0; j < 4; ++j)
                    Qo[(size_t)(row0 + j) * N + col] = (__bf16)acc[m][n][j];
            }
        }
    }
}

// flash attention, transposed-S, PAIRED q-tiles: 512 blocks x uniform 68 iters
// (perfect static fill). QB=128, KB=32 double-buffered, counted vmcnt(4), raw
// barriers, Pl[4][2] single fence. RoPE-Q fused; exp2 softmax; defer-max THR=8;
// diagonal-only masking; deferred l-sum (per-lane partial, epilogue reduce).
__global__ __launch_bounds__(256, 3) void attn_kernel(const __bf16* __restrict__ Q,
                                                      const __bf16* __restrict__ K,
                                                      const __bf16* __restrict__ V,
                                                      __bf16* __restrict__ O,
                                                      const float* __restrict__ ct,
                                                      const float* __restrict__ st) {
    constexpr int QB = 128, KB = 32;
    constexpr int nqb = S_LEN / QB;              // 16
    const int cpx = gridDim.x >> 3;              // 64
    const int b0 = blockIdx.x;
    const int bid = (b0 & 7) * cpx + (b0 >> 3);
    const int pair = bid & 7;
    const int h    = (bid >> 3) & (NH - 1);
    const int b    = bid >> 8;
    const int hkv = h >> 2;
    const int tid = threadIdx.x, lane = tid & 63, w = tid >> 6;
    const int lq = lane & 15, hi2 = lane >> 4;

    __shared__ __bf16 Ks[2][KB * HD];   // [32][128], phys slot s of row r = logical s^(r&7)
    __shared__ __bf16 Vt[2][HD * KB];   // [128][32], phys slot s of row d = logical s^(d&3)
    __shared__ __bf16 Pl[4][2][16][40]; // [wave][mt][q][kv]

    const int qbA = nqb - 1 - pair;      // long pass first
    const int nkbA = 4 * (qbA + 1);
    const int T = nkbA + 4 * (pair + 1); // = 68 for all blocks

    auto stage = [&](int bb, int k0s) {          // 4 DMA issues/thread
        #pragma unroll
        for (int r = 0; r < 2; ++r) {
            int i = r * 256 + tid;
            {   int row = i >> 4, sl = i & 15, lsl = sl ^ (row & 7);
                gl_lds16(&K[((size_t)(b * S_LEN + k0s + row)) * (NKV * HD) + hkv * HD + lsl * 8],
                         &Ks[bb][i * 8]); }
            {   int d = i >> 2, sl = i & 3, lsl = sl ^ (d & 3);
                gl_lds16(&V[((size_t)((b * NKV + hkv) * HD + d)) * S_LEN + k0s + lsl * 8],
                         &Vt[bb][i * 8]); }
        }
    };

    const float c2 = 0.08838834764831843f * 1.4426950408889634f;  // scale * log2(e)

    stage(0, 0);
    int tt = 0;
    #pragma unroll 1
    for (int pass = 0; pass < 2; ++pass) {
        const int qb = pass ? pair : qbA;
        const int q0 = qb * QB, qrow_lo = q0 + w * 32;
        const int nkb = 4 * (qb + 1);

        // Q fragments: load raw Q, apply RoPE + exp2 prescale in-register.
        // chunk c holds d in [c*32+hi2*8, +8); rotation partner of chunk c is c+2.
        bf16x8 qf[2][4];
        #pragma unroll
        for (int mt = 0; mt < 2; ++mt) {
            int row = qrow_lo + mt * 16 + lq;
            const __bf16* qp = Q + ((size_t)(b * S_LEN + row)) * (NH * HD) + h * HD + hi2 * 8;
            const float* cp = ct + ((size_t)(b * S_LEN + row)) * HD + hi2 * 8;
            const float* sp = st + ((size_t)(b * S_LEN + row)) * HD + hi2 * 8;
            #pragma unroll
            for (int c = 0; c < 2; ++c) {
                bf16x8 lo = *(const bf16x8*)(qp + c * 32);
                bf16x8 hi = *(const bf16x8*)(qp + c * 32 + 64);
                f32x4 c0 = *(const f32x4*)(cp + c * 32);
                f32x4 c1 = *(const f32x4*)(cp + c * 32 + 4);
                f32x4 s0 = *(const f32x4*)(sp + c * 32);
                f32x4 s1 = *(const f32x4*)(sp + c * 32 + 4);
                bf16x8 rlo, rhi;
                #pragma unroll
                for (int e = 0; e < 8; ++e) {
                    float cc = ((e < 4) ? c0[e] : c1[e - 4]) * c2;
                    float ss = ((e < 4) ? s0[e] : s1[e - 4]) * c2;
                    float xl = (float)lo[e], xh = (float)hi[e];
                    rlo[e] = (__bf16)(xl * cc - xh * ss);
                    rhi[e] = (__bf16)(xh * cc + xl * ss);
                }
                qf[mt][c]     = rlo;
                qf[mt][c + 2] = rhi;
            }
        }

        f32x4 o_acc[2][8] = {};
        float m_r[2] = {-1e30f, -1e30f}, l_r[2] = {0.f, 0.f};  // l_r = per-lane PARTIAL

        #pragma unroll 1
        for (int kb = 0; kb < nkb; ++kb, ++tt) {
            int tn = (tt + 1 < T) ? tt + 1 : T - 1;
            int k0n = (tn < nkbA ? tn : tn - nkbA) * KB;
            stage((tt + 1) & 1, k0n);
            asm volatile("s_waitcnt vmcnt(4)" ::: "memory");
            SBAR(); SCHEDB();
            const int cur = tt & 1;
            const int k0  = kb * KB;
            const __bf16* ks = &Ks[cur][0];
            const __bf16* vt = &Vt[cur][0];

            // S^T: 32 kv-rows x 16 q-cols per mt; kf shared across both m-tiles
            f32x4 sc[2][2] = {};
            #pragma unroll
            for (int t = 0; t < 2; ++t) {
                int krow = t * 16 + lq;
                #pragma unroll
                for (int c = 0; c < 4; ++c) {
                    int psl = (c * 4 + hi2) ^ (krow & 7);
                    bf16x8 kf = *(const bf16x8*)&ks[krow * HD + psl * 8];
                    sc[0][t] = mfma16(kf, qf[0][c], sc[0][t]);
                    sc[1][t] = mfma16(kf, qf[1][c], sc[1][t]);
                }
            }

            // mask + online softmax + P-write, per m-tile (single fence after both)
            #pragma unroll
            for (int mt = 0; mt < 2; ++mt) {
                int q_abs = qrow_lo + mt * 16 + lq;
                if (k0 + KB - 1 > qrow_lo + mt * 16) {   // diagonal tile: causal mask
                    #pragma unroll
                    for (int t = 0; t < 2; ++t)
                        #pragma unroll
                        for (int j = 0; j < 4; ++j) {
                            int kv_abs = k0 + t * 16 + hi2 * 4 + j;
                            if (kv_abs > q_abs) sc[mt][t][j] = -1e30f;
                        }
                }
                float pmax = fmaxf(
                    fmaxf(fmaxf(sc[mt][0][0], sc[mt][0][1]), fmaxf(sc[mt][0][2], sc[mt][0][3])),
                    fmaxf(fmaxf(sc[mt][1][0], sc[mt][1][1]), fmaxf(sc[mt][1][2], sc[mt][1][3])));
                pmax = fmaxf(pmax, __shfl_xor(pmax, 16));
                pmax = fmaxf(pmax, __shfl_xor(pmax, 32));
                if (!__all(pmax - m_r[mt] <= 8.0f)) {    // defer-max (wave-uniform branch)
                    float mn = fmaxf(m_r[mt], pmax);
                    float sf = __builtin_amdgcn_exp2f(m_r[mt] - mn);
                    m_r[mt] = mn;
                    l_r[mt] *= sf;                       // partial scaled consistently
                    #pragma unroll
                    for (int dt = 0; dt < 8; ++dt)
                        #pragma unroll
                        for (int j = 0; j < 4; ++j) o_acc[mt][dt][j] *= sf;
                }
                float rs = 0.f;
                #pragma unroll
                for (int t = 0; t < 2; ++t)
                    #pragma unroll
                    for (int j = 0; j < 4; ++j) {
                        float p = __builtin_amdgcn_exp2f(sc[mt][t][j] - m_r[mt]);
                        sc[mt][t][j] = p;
                        rs += p;
                    }
                l_r[mt] += rs;                           // deferred: no per-iter shuffles
                #pragma unroll
                for (int t = 0; t < 2; ++t) {
                    bf16x4 pw;
                    #pragma unroll
                    for (int j = 0; j < 4; ++j) pw[j] = (__bf16)sc[mt][t][j];
                    *(bf16x4*)&Pl[w][mt][lq][t * 16 + hi2 * 4] = pw;
                }
            }

            LGKM0(); SCHEDB();
            bf16x8 pf0 = *(const bf16x8*)&Pl[w][0][lq][hi2 * 8];
            bf16x8 pf1 = *(const bf16x8*)&Pl[w][1][lq][hi2 * 8];

            // PV: 8 d-tiles; vf shared across both m-tiles
            #pragma unroll
            for (int dt = 0; dt < 8; ++dt) {
                int vrow = dt * 16 + lq;
                int psl  = hi2 ^ (vrow & 3);
                bf16x8 vf = *(const bf16x8*)&vt[vrow * KB + psl * 8];
                o_acc[0][dt] = mfma16(vf, pf0, o_acc[0][dt]);
                o_acc[1][dt] = mfma16(vf, pf1, o_acc[1][dt]);
            }
            LGKM0(); SCHEDB();     // all cur ds_reads complete before next-iter DMA
            SBAR(); SCHEDB();
        }

        #pragma unroll
        for (int mt = 0; mt < 2; ++mt) {
            float lsum = l_r[mt];                        // reduce partials now
            lsum += __shfl_xor(lsum, 16);
            lsum += __shfl_xor(lsum, 32);
            float inv = 1.0f / lsum;
            int q_abs = qrow_lo + mt * 16 + lq;
            __bf16* op = O + ((size_t)(b * S_LEN + q_abs)) * (NH * HD) + h * HD;
            #pragma unroll
            for (int dt = 0; dt < 8; ++dt) {
                bf16x4 t4;
                #pragma unroll
                for (int j = 0; j < 4; ++j) t4[j] = (__bf16)(o_acc[mt][dt][j] * inv);
                *(bf16x4*)&op[dt * 16 + hi2 * 4] = t4;
            }
        }
    }
}

extern "C" void kernel_launch(void* const* d_in, const int* in_sizes, int n_in,
                              void* d_out, int out_size, void* d_ws, size_t ws_size,
                              hipStream_t stream) {
    const float* X  = (const float*)d_in[0];
    // d_in[1] = attention_mask: exactly causal; applied analytically in attn_kernel
    const float* ct = (const float*)d_in[2];
    const float* st = (const float*)d_in[3];
    const float* Wq = (const float*)d_in[4];
    const float* Wk = (const float*)d_in[5];
    const float* Wv = (const float*)d_in[6];
    const float* Wo = (const float*)d_in[7];
    float* out = (float*)d_out;

    const size_t MEL  = (size_t)MROWS * HIDDEN;      // 16.78M
    const size_t KVEL = (size_t)MROWS * (NKV * HD);  // 4.19M
    const int NQKV = NH * HD + 2 * NKV * HD;         // 6144

    // workspace (134.2 MB), dead-buffer aliasing.
    // ORDERING CONSTRAINT: Wob aliases Xb -> Wo conversion must run AFTER the
    // Q/KV projections consume Xb.
    __bf16* Wqkv = (__bf16*)d_ws;                   // [6144][4096] -> reused as Ab
    __bf16* Xb   = Wqkv + (size_t)NQKV * HIDDEN;    // [4096][4096] -> reused as Wob
    __bf16* Qb   = Xb + MEL;
    __bf16* Kb   = Qb + MEL;
    __bf16* VtG  = Kb + KVEL;
    __bf16* Ab   = Wqkv;
    __bf16* Wob  = Xb;

    dim3 blk(256);
    // fused conversions: X->Xb, Wq/Wk/Wv -> Wqkv (contiguous regions)
    const int cbM = (int)(MEL / 8 / 256);    // 8192 blocks per MEL segment
    const int cbK = (int)(KVEL / 8 / 256);   // 2048 blocks per KVEL segment
    hipLaunchKernelGGL(conv4, dim3(2 * cbM + 2 * cbK), blk, 0, stream,
                       X,  Xb, cbM,
                       Wq, Wqkv, cbM,
                       Wk, Wqkv + (size_t)HIDDEN * HIDDEN, cbK,
                       Wv, Wqkv + (size_t)(HIDDEN + NKV * HD) * HIDDEN);

    // Q projection: 4096x4096x4096, 256 blocks (exact machine fill); Qb is pre-RoPE
    hipLaunchKernelGGL((gemm256<0, 256>), dim3(256), dim3(512), 0, stream,
                       Xb, Wqkv, nullptr, Qb, nullptr, nullptr, NH * HD, HIDDEN, 16);
    // KV projection: 4096x2048x4096, BM=128 -> 256 blocks (exact fill)
    hipLaunchKernelGGL((gemm256<3, 128>), dim3(256), dim3(512), 0, stream,
                       Xb, Wqkv + (size_t)HIDDEN * HIDDEN, nullptr, nullptr, Kb, VtG,
                       2 * NKV * HD, HIDDEN, 8);

    // fused: RoPE-K (Q roped in-register inside attn) + Wo conversion.
    // Runs after both projections -> Xb is dead, safe to overwrite as Wob.
    const int ropeB = (MROWS * NKV * 64) / 256;      // 8192
    hipLaunchKernelGGL(rope_conv, dim3(ropeB + cbM), blk, 0, stream,
                       Kb, ct, st, ropeB, Wo, Wob);

    // attention: 8 pairs x 32 heads x 2 batch = 512 uniform blocks (68 iters each)
    hipLaunchKernelGGL(attn_kernel, dim3(512), blk, 0, stream, Qb, Kb, VtG, Ab, ct, st);

    // O projection: 4096x4096x4096 -> fp32 out, 256 blocks (exact fill)
    hipLaunchKernelGGL((gemm256<1, 256>), dim3(256), dim3(512), 0, stream,
                       Ab, Wob, out, nullptr, nullptr, nullptr, HIDDEN, HIDDEN, 16);
}